// Round 2
// baseline (3118.285 us; speedup 1.0000x reference)
//
#include <hip/hip_runtime.h>
#include <math.h>

#define T_TOK 8192   // m*s = 4*2048 tokens
#define E_DIM 1024
#define S_LEN 2048

// ---------------------------------------------------------------------------
// Kernel 1: per-token gate softmax for all 3 projections.
// grid: (8192), block: 64 (one wave per token). gates[p][t][n], p in {q,k,v}.
// ---------------------------------------------------------------------------
__global__ __launch_bounds__(64) void gates_kernel(
    const float* __restrict__ x,
    const float* __restrict__ Wgq, const float* __restrict__ bgq,
    const float* __restrict__ Wgk, const float* __restrict__ bgk,
    const float* __restrict__ Wgv, const float* __restrict__ bgv,
    float* __restrict__ gates) {
  const int t = blockIdx.x;
  const int lane = threadIdx.x;
  const float* xr = x + (size_t)t * E_DIM;
  float acc[9];
#pragma unroll
  for (int i = 0; i < 9; ++i) acc[i] = 0.f;
  for (int e = lane; e < E_DIM; e += 64) {
    const float xv = xr[e];
    acc[0] = fmaf(xv, Wgq[e * 3 + 0], acc[0]);
    acc[1] = fmaf(xv, Wgq[e * 3 + 1], acc[1]);
    acc[2] = fmaf(xv, Wgq[e * 3 + 2], acc[2]);
    acc[3] = fmaf(xv, Wgk[e * 3 + 0], acc[3]);
    acc[4] = fmaf(xv, Wgk[e * 3 + 1], acc[4]);
    acc[5] = fmaf(xv, Wgk[e * 3 + 2], acc[5]);
    acc[6] = fmaf(xv, Wgv[e * 3 + 0], acc[6]);
    acc[7] = fmaf(xv, Wgv[e * 3 + 1], acc[7]);
    acc[8] = fmaf(xv, Wgv[e * 3 + 2], acc[8]);
  }
#pragma unroll
  for (int off = 32; off > 0; off >>= 1) {
#pragma unroll
    for (int i = 0; i < 9; ++i) acc[i] += __shfl_down(acc[i], off, 64);
  }
  if (lane == 0) {
    const float* bg[3] = {bgq, bgk, bgv};
#pragma unroll
    for (int p = 0; p < 3; ++p) {
      float z0 = acc[p * 3 + 0] + bg[p][0];
      float z1 = acc[p * 3 + 1] + bg[p][1];
      float z2 = acc[p * 3 + 2] + bg[p][2];
      float mx = fmaxf(z0, fmaxf(z1, z2));
      float e0 = expf(z0 - mx), e1 = expf(z1 - mx), e2 = expf(z2 - mx);
      float inv = 1.f / (e0 + e1 + e2);
      float* gp = gates + ((size_t)p * T_TOK + t) * 3;
      gp[0] = e0 * inv;
      gp[1] = e1 * inv;
      gp[2] = e2 * inv;
    }
  }
}

// ---------------------------------------------------------------------------
// Kernel 2: MoE expert GEMM, gate folded into the A operand:
//   out[t,o] = sum_n (g[t,n]*x[t,:]) @ W_n[:,o]  + sum_n g[t,n]*b_n[o]
// One GEMM with effective K = 3*1024 = 3072.
// Tile 128x128xBK8, 256 threads, 8x8 micro-tile per thread (split-half
// row/col mapping so LDS float4 reads are conflict-free / 2-way max).
// grid: (8192/128, 1024/128, 3 projections)
// ---------------------------------------------------------------------------
__global__ __launch_bounds__(256) void moe_gemm_kernel(
    const float* __restrict__ x,
    const float* __restrict__ Wq_, const float* __restrict__ bq_,
    const float* __restrict__ Wk_, const float* __restrict__ bk_,
    const float* __restrict__ Wv_, const float* __restrict__ bv_,
    const float* __restrict__ gates,
    float* __restrict__ oq_, float* __restrict__ ok_, float* __restrict__ ov_) {
  const int p = blockIdx.z;
  const float* W = (p == 0) ? Wq_ : (p == 1) ? Wk_ : Wv_;
  const float* bias = (p == 0) ? bq_ : (p == 1) ? bk_ : bv_;
  float* out = (p == 0) ? oq_ : (p == 1) ? ok_ : ov_;
  const float* gbase = gates + (size_t)p * T_TOK * 3;

  __shared__ float AsT[8][128];  // [k][m] transposed A tile (gate-scaled x)
  __shared__ float Bs[8][128];   // [k][n] W tile
  __shared__ float gsh[128][3];  // gates for this block's 128 tokens

  const int tid = threadIdx.x;
  const int tx = tid & 15;        // 0..15 col group
  const int ty = tid >> 4;        // 0..15 row group
  const int row0 = blockIdx.x * 128;
  const int col0 = blockIdx.y * 128;

  for (int i = tid; i < 384; i += 256)
    gsh[i / 3][i % 3] = gbase[(size_t)(row0 + i / 3) * 3 + (i % 3)];

  float acc[8][8];
#pragma unroll
  for (int i = 0; i < 8; ++i)
#pragma unroll
    for (int j = 0; j < 8; ++j) acc[i][j] = 0.f;

  __syncthreads();  // gsh ready (A staging reads it)

  const int ar = tid >> 1;          // 0..127 token row
  const int ac = (tid & 1) << 2;    // 0 or 4 (k within tile)
  const int br = tid >> 5;          // 0..7 k row
  const int bc = (tid & 31) << 2;   // 0..124 col
  const float* xrow = x + (size_t)(row0 + ar) * E_DIM + ac;

  for (int kk = 0; kk < 3072; kk += 8) {
    const int n = kk >> 10;      // expert index
    const int k = kk & 1023;     // k within expert
    // stage A (transposed, gate-scaled)
    const float g = gsh[ar][n];
    const float4 av = *(const float4*)(xrow + k);
    AsT[ac + 0][ar] = av.x * g;
    AsT[ac + 1][ar] = av.y * g;
    AsT[ac + 2][ar] = av.z * g;
    AsT[ac + 3][ar] = av.w * g;
    // stage B
    *(float4*)(&Bs[br][bc]) =
        *(const float4*)(W + (size_t)n * 1048576 + (size_t)(k + br) * 1024 + col0 + bc);
    __syncthreads();
#pragma unroll
    for (int kq = 0; kq < 8; ++kq) {
      const float4 a0 = *(const float4*)(&AsT[kq][ty * 4]);
      const float4 a1 = *(const float4*)(&AsT[kq][64 + ty * 4]);
      const float4 b0 = *(const float4*)(&Bs[kq][tx * 4]);
      const float4 b1 = *(const float4*)(&Bs[kq][64 + tx * 4]);
      const float a[8] = {a0.x, a0.y, a0.z, a0.w, a1.x, a1.y, a1.z, a1.w};
      const float b[8] = {b0.x, b0.y, b0.z, b0.w, b1.x, b1.y, b1.z, b1.w};
#pragma unroll
      for (int i = 0; i < 8; ++i)
#pragma unroll
        for (int j = 0; j < 8; ++j) acc[i][j] = fmaf(a[i], b[j], acc[i][j]);
    }
    __syncthreads();
  }

  // epilogue: + sum_n g_n * b_n[col], write fp32
#pragma unroll
  for (int ih = 0; ih < 2; ++ih) {
#pragma unroll
    for (int i = 0; i < 4; ++i) {
      const int rl = ih * 64 + ty * 4 + i;
      const float g0 = gsh[rl][0], g1 = gsh[rl][1], g2 = gsh[rl][2];
      float* orow = out + (size_t)(row0 + rl) * E_DIM;
#pragma unroll
      for (int jh = 0; jh < 2; ++jh) {
        const int cl = jh * 64 + tx * 4;
        const int c = col0 + cl;
        float4 v;
        v.x = acc[ih * 4 + i][jh * 4 + 0] + g0 * bias[c + 0] + g1 * bias[1024 + c + 0] + g2 * bias[2048 + c + 0];
        v.y = acc[ih * 4 + i][jh * 4 + 1] + g0 * bias[c + 1] + g1 * bias[1024 + c + 1] + g2 * bias[2048 + c + 1];
        v.z = acc[ih * 4 + i][jh * 4 + 2] + g0 * bias[c + 2] + g1 * bias[1024 + c + 2] + g2 * bias[2048 + c + 2];
        v.w = acc[ih * 4 + i][jh * 4 + 3] + g0 * bias[c + 3] + g1 * bias[1024 + c + 3] + g2 * bias[2048 + c + 3];
        *(float4*)(orow + c) = v;
      }
    }
  }
}

// ---------------------------------------------------------------------------
// Kernel 3: flash attention, fp32. One block = one (m,h) head and one 64-row
// Q tile; iterate 32 K/V tiles of 64 keys with online softmax.
// grid: (2048/64, m*H) = (32, 64), block 256.
// ---------------------------------------------------------------------------
__global__ __launch_bounds__(256) void attn_kernel(
    const float* __restrict__ xq, const float* __restrict__ xk,
    const float* __restrict__ xv, float* __restrict__ out) {
  __shared__ float QsT[64][64];   // [d][q]
  __shared__ float KsT[64][64];   // [d][k]
  __shared__ float Vs[64][64];    // [k][d]
  __shared__ float Ss[64][65];    // [q][k], padded
  __shared__ float mstate[64], lstate[64], alphas[64];

  const int tid = threadIdx.x;
  const int tx = tid & 15;   // d col group
  const int ty = tid >> 4;   // q row group
  const int qt0 = blockIdx.x * 64;
  const int mh = blockIdx.y;
  const int mi = mh >> 4, h = mh & 15;
  const size_t base = ((size_t)mi * S_LEN) * E_DIM + (size_t)h * 64;

  // stage Q (transposed)
  for (int it = tid; it < 1024; it += 256) {
    const int row = it >> 4, c4 = (it & 15) << 2;
    const float4 qv = *(const float4*)(xq + base + (size_t)(qt0 + row) * E_DIM + c4);
    QsT[c4 + 0][row] = qv.x;
    QsT[c4 + 1][row] = qv.y;
    QsT[c4 + 2][row] = qv.z;
    QsT[c4 + 3][row] = qv.w;
  }
  if (tid < 64) {
    mstate[tid] = -3.0e38f;
    lstate[tid] = 0.f;
  }
  float o[4][4];
#pragma unroll
  for (int i = 0; i < 4; ++i)
#pragma unroll
    for (int j = 0; j < 4; ++j) o[i][j] = 0.f;

  for (int jt = 0; jt < 32; ++jt) {
    __syncthreads();  // protect KsT/Vs/Ss from previous iteration consumers
    const int kt0 = jt * 64;
    for (int it = tid; it < 1024; it += 256) {
      const int row = it >> 4, c4 = (it & 15) << 2;
      const size_t ga = base + (size_t)(kt0 + row) * E_DIM + c4;
      const float4 kv = *(const float4*)(xk + ga);
      KsT[c4 + 0][row] = kv.x;
      KsT[c4 + 1][row] = kv.y;
      KsT[c4 + 2][row] = kv.z;
      KsT[c4 + 3][row] = kv.w;
      *(float4*)(&Vs[row][c4]) = *(const float4*)(xv + ga);
    }
    __syncthreads();

    // S = Q K^T * 1/sqrt(64)
    float s[4][4];
#pragma unroll
    for (int i = 0; i < 4; ++i)
#pragma unroll
      for (int j = 0; j < 4; ++j) s[i][j] = 0.f;
#pragma unroll 8
    for (int d = 0; d < 64; ++d) {
      const float4 a4 = *(const float4*)(&QsT[d][ty * 4]);
      const float4 b4 = *(const float4*)(&KsT[d][tx * 4]);
      const float a[4] = {a4.x, a4.y, a4.z, a4.w};
      const float b[4] = {b4.x, b4.y, b4.z, b4.w};
#pragma unroll
      for (int i = 0; i < 4; ++i)
#pragma unroll
        for (int j = 0; j < 4; ++j) s[i][j] = fmaf(a[i], b[j], s[i][j]);
    }
#pragma unroll
    for (int i = 0; i < 4; ++i)
#pragma unroll
      for (int j = 0; j < 4; ++j) Ss[ty * 4 + i][tx * 4 + j] = s[i][j] * 0.125f;
    __syncthreads();

    // online softmax: 4 lanes per q-row (same wave -> lockstep)
    {
      const int q = tid >> 2, part = tid & 3;
      const int k0 = part * 16;
      const float mprev = mstate[q];
      float mcur = -3.0e38f;
#pragma unroll
      for (int k2 = 0; k2 < 16; ++k2) mcur = fmaxf(mcur, Ss[q][k0 + k2]);
      mcur = fmaxf(mcur, __shfl_xor(mcur, 1, 64));
      mcur = fmaxf(mcur, __shfl_xor(mcur, 2, 64));
      const float mnew = fmaxf(mprev, mcur);
      float rs = 0.f;
#pragma unroll
      for (int k2 = 0; k2 < 16; ++k2) {
        const float pv = __expf(Ss[q][k0 + k2] - mnew);
        Ss[q][k0 + k2] = pv;
        rs += pv;
      }
      rs += __shfl_xor(rs, 1, 64);
      rs += __shfl_xor(rs, 2, 64);
      if (part == 0) {
        const float alpha = __expf(mprev - mnew);
        lstate[q] = lstate[q] * alpha + rs;
        mstate[q] = mnew;
        alphas[q] = alpha;
      }
    }
    __syncthreads();

    // O = O*alpha + P V
    float al[4];
#pragma unroll
    for (int i = 0; i < 4; ++i) al[i] = alphas[ty * 4 + i];
#pragma unroll
    for (int i = 0; i < 4; ++i)
#pragma unroll
      for (int j = 0; j < 4; ++j) o[i][j] *= al[i];
#pragma unroll 8
    for (int k2 = 0; k2 < 64; ++k2) {
      float pr[4];
#pragma unroll
      for (int i = 0; i < 4; ++i) pr[i] = Ss[ty * 4 + i][k2];
      const float4 v4 = *(const float4*)(&Vs[k2][tx * 4]);
#pragma unroll
      for (int i = 0; i < 4; ++i) {
        o[i][0] = fmaf(pr[i], v4.x, o[i][0]);
        o[i][1] = fmaf(pr[i], v4.y, o[i][1]);
        o[i][2] = fmaf(pr[i], v4.z, o[i][2]);
        o[i][3] = fmaf(pr[i], v4.w, o[i][3]);
      }
    }
  }

  // epilogue: divide by l, store
#pragma unroll
  for (int i = 0; i < 4; ++i) {
    const float linv = 1.f / lstate[ty * 4 + i];
    float4 v;
    v.x = o[i][0] * linv;
    v.y = o[i][1] * linv;
    v.z = o[i][2] * linv;
    v.w = o[i][3] * linv;
    *(float4*)(out + base + (size_t)(qt0 + ty * 4 + i) * E_DIM + tx * 4) = v;
  }
}

// ---------------------------------------------------------------------------
extern "C" void kernel_launch(void* const* d_in, const int* in_sizes, int n_in,
                              void* d_out, int out_size, void* d_ws, size_t ws_size,
                              hipStream_t stream) {
  (void)in_sizes; (void)n_in; (void)out_size;
  const float* x   = (const float*)d_in[0];
  const float* Wq  = (const float*)d_in[1];
  const float* bq  = (const float*)d_in[2];
  const float* Wgq = (const float*)d_in[3];
  const float* bgq = (const float*)d_in[4];
  const float* Wk  = (const float*)d_in[5];
  const float* bk  = (const float*)d_in[6];
  const float* Wgk = (const float*)d_in[7];
  const float* bgk = (const float*)d_in[8];
  const float* Wv  = (const float*)d_in[9];
  const float* bv  = (const float*)d_in[10];
  const float* Wgv = (const float*)d_in[11];
  const float* bgv = (const float*)d_in[12];
  float* out = (float*)d_out;

  // workspace layout: gates (3*8192*3 f32) | xq | xk | xv
  const size_t need = 294912 + 3 * (size_t)T_TOK * E_DIM * sizeof(float);  // ~101 MB
  if (ws_size < need) return;  // refuse to scribble OOB (fails validation cleanly)

  float* gates = (float*)d_ws;
  float* xq = (float*)((char*)d_ws + 294912);
  float* xk = xq + (size_t)T_TOK * E_DIM;
  float* xv = xk + (size_t)T_TOK * E_DIM;

  gates_kernel<<<dim3(T_TOK), dim3(64), 0, stream>>>(x, Wgq, bgq, Wgk, bgk, Wgv, bgv, gates);
  moe_gemm_kernel<<<dim3(T_TOK / 128, E_DIM / 128, 3), dim3(256), 0, stream>>>(
      x, Wq, bq, Wk, bk, Wv, bv, gates, xq, xk, xv);
  attn_kernel<<<dim3(S_LEN / 64, 64), dim3(256), 0, stream>>>(xq, xk, xv, out);
}

// Round 3
// 1849.260 us; speedup vs baseline: 1.6862x; 1.6862x over previous
//
#include <hip/hip_runtime.h>
#include <math.h>

#define T_TOK 8192   // m*s = 4*2048 tokens
#define E_DIM 1024
#define S_LEN 2048

typedef _Float16 f16x4 __attribute__((ext_vector_type(4)));
typedef _Float16 f16x8 __attribute__((ext_vector_type(8)));
typedef float f32x16 __attribute__((ext_vector_type(16)));

// async global->LDS 16B: LDS dst is wave-uniform base + lane*16 (contiguous).
__device__ __forceinline__ void async16(const void* g, void* l) {
  __builtin_amdgcn_global_load_lds(
      (const __attribute__((address_space(1))) void*)g,
      (__attribute__((address_space(3))) void*)l, 16, 0, 0);
}

// ---------------------------------------------------------------------------
// Kernel 1: per-token gate softmax for all 3 projections.
// ---------------------------------------------------------------------------
__global__ __launch_bounds__(64) void gates_kernel(
    const float* __restrict__ x,
    const float* __restrict__ Wgq, const float* __restrict__ bgq,
    const float* __restrict__ Wgk, const float* __restrict__ bgk,
    const float* __restrict__ Wgv, const float* __restrict__ bgv,
    float* __restrict__ gates) {
  const int t = blockIdx.x;
  const int lane = threadIdx.x;
  const float* xr = x + (size_t)t * E_DIM;
  float acc[9];
#pragma unroll
  for (int i = 0; i < 9; ++i) acc[i] = 0.f;
  for (int e = lane; e < E_DIM; e += 64) {
    const float xv = xr[e];
    acc[0] = fmaf(xv, Wgq[e * 3 + 0], acc[0]);
    acc[1] = fmaf(xv, Wgq[e * 3 + 1], acc[1]);
    acc[2] = fmaf(xv, Wgq[e * 3 + 2], acc[2]);
    acc[3] = fmaf(xv, Wgk[e * 3 + 0], acc[3]);
    acc[4] = fmaf(xv, Wgk[e * 3 + 1], acc[4]);
    acc[5] = fmaf(xv, Wgk[e * 3 + 2], acc[5]);
    acc[6] = fmaf(xv, Wgv[e * 3 + 0], acc[6]);
    acc[7] = fmaf(xv, Wgv[e * 3 + 1], acc[7]);
    acc[8] = fmaf(xv, Wgv[e * 3 + 2], acc[8]);
  }
#pragma unroll
  for (int off = 32; off > 0; off >>= 1) {
#pragma unroll
    for (int i = 0; i < 9; ++i) acc[i] += __shfl_down(acc[i], off, 64);
  }
  if (lane == 0) {
    const float* bg[3] = {bgq, bgk, bgv};
#pragma unroll
    for (int p = 0; p < 3; ++p) {
      float z0 = acc[p * 3 + 0] + bg[p][0];
      float z1 = acc[p * 3 + 1] + bg[p][1];
      float z2 = acc[p * 3 + 2] + bg[p][2];
      float mx = fmaxf(z0, fmaxf(z1, z2));
      float e0 = expf(z0 - mx), e1 = expf(z1 - mx), e2 = expf(z2 - mx);
      float inv = 1.f / (e0 + e1 + e2);
      float* gp = gates + ((size_t)p * T_TOK + t) * 3;
      gp[0] = e0 * inv;
      gp[1] = e1 * inv;
      gp[2] = e2 * inv;
    }
  }
}

// ---------------------------------------------------------------------------
// Kernel P1: split x (fp32) -> xh + xl (f16 hi/lo), same [t][k] layout.
// grid: 8192 blocks x 256 thr, 4 elems/thread.
// ---------------------------------------------------------------------------
__global__ __launch_bounds__(256) void split_x_kernel(
    const float* __restrict__ x, _Float16* __restrict__ xh, _Float16* __restrict__ xl) {
  const size_t i = ((size_t)blockIdx.x * 256 + threadIdx.x) * 4;
  const float4 v = *(const float4*)(x + i);
  f16x4 h, lo;
  h[0] = (_Float16)v.x; lo[0] = (_Float16)(v.x - (float)h[0]);
  h[1] = (_Float16)v.y; lo[1] = (_Float16)(v.y - (float)h[1]);
  h[2] = (_Float16)v.z; lo[2] = (_Float16)(v.z - (float)h[2]);
  h[3] = (_Float16)v.w; lo[3] = (_Float16)(v.w - (float)h[3]);
  *(f16x4*)(xh + i) = h;
  *(f16x4*)(xl + i) = lo;
}

// ---------------------------------------------------------------------------
// Kernel P2: split + transpose W. In: W[mat][k][c] fp32 (mat = p*3+e).
// Out: wh/wl[mat][c][k] f16 (k contiguous -> MFMA B-frag ready).
// grid: (256 tiles of 64x64, 9 mats), block 256.
// ---------------------------------------------------------------------------
__global__ __launch_bounds__(256) void split_w_kernel(
    const float* __restrict__ Wq, const float* __restrict__ Wk, const float* __restrict__ Wv,
    _Float16* __restrict__ wh, _Float16* __restrict__ wl) {
  const int mat = blockIdx.y;
  const float* W = ((mat < 3) ? Wq : (mat < 6) ? Wk : Wv) + (size_t)(mat % 3) * 1048576;
  const int kt = (blockIdx.x >> 4) * 64, ct = (blockIdx.x & 15) * 64;
  __shared__ _Float16 hs[64][72];  // [c][k], pad 72 (144B rows, 16B-aligned)
  __shared__ _Float16 ls[64][72];
  const int tid = threadIdx.x;
#pragma unroll
  for (int i = 0; i < 4; ++i) {
    const int r = (tid >> 4) + i * 16;        // k-row in tile
    const int c4 = (tid & 15) * 4;            // col in tile
    const float4 v = *(const float4*)(W + (size_t)(kt + r) * 1024 + ct + c4);
    _Float16 h;
    h = (_Float16)v.x; hs[c4 + 0][r] = h; ls[c4 + 0][r] = (_Float16)(v.x - (float)h);
    h = (_Float16)v.y; hs[c4 + 1][r] = h; ls[c4 + 1][r] = (_Float16)(v.y - (float)h);
    h = (_Float16)v.z; hs[c4 + 2][r] = h; ls[c4 + 2][r] = (_Float16)(v.z - (float)h);
    h = (_Float16)v.w; hs[c4 + 3][r] = h; ls[c4 + 3][r] = (_Float16)(v.w - (float)h);
  }
  __syncthreads();
#pragma unroll
  for (int i = 0; i < 2; ++i) {
    const int u = tid + i * 256;
    const int c = u >> 3, seg = u & 7;
    const size_t o = (size_t)mat * 1048576 + (size_t)(ct + c) * 1024 + kt + seg * 8;
    *(f16x8*)(wh + o) = *(const f16x8*)(&hs[c][seg * 8]);
    *(f16x8*)(wl + o) = *(const f16x8*)(&ls[c][seg * 8]);
  }
}

// ---------------------------------------------------------------------------
// Kernel 2 (MFMA): MoE expert GEMM, f16 hi/lo 3-pass, 32x32x16 MFMA.
// out[t,o] = sum_e g[t,e]*( x[t,:] @ W_e[:,o] + b_e[o] )
// Block 128x128, 4 waves each 2x2 tiles of 32x32; BK=32; expert-outer loop
// with per-expert AGPR acc folded into fin by the per-row gate.
// grid: (64, 8, 3 projections).
// ---------------------------------------------------------------------------
__global__ __launch_bounds__(256, 2) void moe_mfma_kernel(
    const _Float16* __restrict__ xh, const _Float16* __restrict__ xl,
    const _Float16* __restrict__ wh, const _Float16* __restrict__ wl,
    const float* __restrict__ bq_, const float* __restrict__ bk_, const float* __restrict__ bv_,
    const float* __restrict__ gates,
    float* __restrict__ oq_, float* __restrict__ ok_, float* __restrict__ ov_) {
  const int p = blockIdx.z;
  const float* bias = (p == 0) ? bq_ : (p == 1) ? bk_ : bv_;
  float* out = (p == 0) ? oq_ : (p == 1) ? ok_ : ov_;

  __shared__ _Float16 Ah[128][32], Al[128][32], Bh[128][32], Bl[128][32];
  __shared__ float gsh[128][3];
  __shared__ float bsh[3][128];

  const int tid = threadIdx.x;
  const int l = tid & 63, w = tid >> 6;
  const int wm = w & 1, wn = w >> 1;
  const int row0 = blockIdx.x * 128, col0 = blockIdx.y * 128;

  for (int i = tid; i < 384; i += 256)
    gsh[i / 3][i % 3] = gates[((size_t)p * T_TOK + row0 + i / 3) * 3 + (i % 3)];
  for (int i = tid; i < 384; i += 256)
    bsh[i >> 7][i & 127] = bias[(i >> 7) * 1024 + col0 + (i & 127)];

  // MFMA frag lane constants
  const int m = l & 31, half = l >> 5;
  const int S = (m >> 1) & 3;  // XOR chunk swizzle key (row-based)
  // staging lane constants: lane covers (row = w*32 [+16] + (l>>2), chunk gc)
  const int rr = l >> 2;
  const int gc = (l & 3) ^ ((l >> 3) & 3);  // swizzled source chunk
  const size_t aoff = (size_t)(row0 + w * 32 + rr) * 1024 + gc * 8;

  f32x16 fin[2][2];
#pragma unroll
  for (int i = 0; i < 2; ++i)
#pragma unroll
    for (int j = 0; j < 2; ++j)
#pragma unroll
      for (int r = 0; r < 16; ++r) fin[i][j][r] = 0.f;

  for (int e = 0; e < 3; ++e) {
    f32x16 acc[2][2];
#pragma unroll
    for (int i = 0; i < 2; ++i)
#pragma unroll
      for (int j = 0; j < 2; ++j)
#pragma unroll
        for (int r = 0; r < 16; ++r) acc[i][j][r] = 0.f;

    const size_t wbase = ((size_t)(p * 3 + e) * 1024 + col0 + w * 32 + rr) * 1024 + gc * 8;

    for (int ks = 0; ks < 32; ++ks) {
      const int k0 = ks * 32;
      __syncthreads();  // previous stage's frag reads done
      async16(xh + aoff + k0,             &Ah[w * 32][0]);
      async16(xh + aoff + k0 + 16 * 1024, &Ah[w * 32 + 16][0]);
      async16(xl + aoff + k0,             &Al[w * 32][0]);
      async16(xl + aoff + k0 + 16 * 1024, &Al[w * 32 + 16][0]);
      async16(wh + wbase + k0,             &Bh[w * 32][0]);
      async16(wh + wbase + k0 + 16 * 1024, &Bh[w * 32 + 16][0]);
      async16(wl + wbase + k0,             &Bl[w * 32][0]);
      async16(wl + wbase + k0 + 16 * 1024, &Bl[w * 32 + 16][0]);
      __syncthreads();  // drains vmcnt (compiler emits waitcnt before barrier)

#pragma unroll
      for (int ss = 0; ss < 2; ++ss) {
        const int ch = ((ss << 1) | half) ^ S;
        f16x8 a_h[2], a_l[2], b_h[2], b_l[2];
#pragma unroll
        for (int i = 0; i < 2; ++i) {
          const int rA = wm * 64 + i * 32 + m;
          a_h[i] = *(const f16x8*)(&Ah[rA][ch * 8]);
          a_l[i] = *(const f16x8*)(&Al[rA][ch * 8]);
          const int rB = wn * 64 + i * 32 + m;
          b_h[i] = *(const f16x8*)(&Bh[rB][ch * 8]);
          b_l[i] = *(const f16x8*)(&Bl[rB][ch * 8]);
        }
#pragma unroll
        for (int i = 0; i < 2; ++i)
#pragma unroll
          for (int j = 0; j < 2; ++j) {
            acc[i][j] = __builtin_amdgcn_mfma_f32_32x32x16_f16(a_h[i], b_h[j], acc[i][j], 0, 0, 0);
            acc[i][j] = __builtin_amdgcn_mfma_f32_32x32x16_f16(a_h[i], b_l[j], acc[i][j], 0, 0, 0);
            acc[i][j] = __builtin_amdgcn_mfma_f32_32x32x16_f16(a_l[i], b_h[j], acc[i][j], 0, 0, 0);
          }
      }
    }
    // fold this expert into fin with the per-row gate
#pragma unroll
    for (int i = 0; i < 2; ++i)
#pragma unroll
      for (int r = 0; r < 16; ++r) {
        const int row_l = wm * 64 + i * 32 + (r & 3) + ((r >> 2) << 3) + (half << 2);
        const float g = gsh[row_l][e];
#pragma unroll
        for (int j = 0; j < 2; ++j) fin[i][j][r] += g * acc[i][j][r];
      }
  }

  // epilogue: + sum_e g_e(row)*b_e(col); store fp32
#pragma unroll
  for (int j = 0; j < 2; ++j) {
    const int col_l = wn * 64 + j * 32 + m;
    const float b0 = bsh[0][col_l], b1 = bsh[1][col_l], b2 = bsh[2][col_l];
#pragma unroll
    for (int i = 0; i < 2; ++i)
#pragma unroll
      for (int r = 0; r < 16; ++r) {
        const int row_l = wm * 64 + i * 32 + (r & 3) + ((r >> 2) << 3) + (half << 2);
        const float g0 = gsh[row_l][0], g1 = gsh[row_l][1], g2 = gsh[row_l][2];
        out[(size_t)(row0 + row_l) * 1024 + col0 + col_l] =
            fin[i][j][r] + g0 * b0 + g1 * b1 + g2 * b2;
      }
  }
}

// ---------------------------------------------------------------------------
// Kernel 2-fallback (fp32 VALU), used only if ws_size is too small for split
// buffers. Same as round-2 kernel.
// ---------------------------------------------------------------------------
__global__ __launch_bounds__(256) void moe_gemm_kernel(
    const float* __restrict__ x,
    const float* __restrict__ Wq_, const float* __restrict__ bq_,
    const float* __restrict__ Wk_, const float* __restrict__ bk_,
    const float* __restrict__ Wv_, const float* __restrict__ bv_,
    const float* __restrict__ gates,
    float* __restrict__ oq_, float* __restrict__ ok_, float* __restrict__ ov_) {
  const int p = blockIdx.z;
  const float* W = (p == 0) ? Wq_ : (p == 1) ? Wk_ : Wv_;
  const float* bias = (p == 0) ? bq_ : (p == 1) ? bk_ : bv_;
  float* out = (p == 0) ? oq_ : (p == 1) ? ok_ : ov_;
  const float* gbase = gates + (size_t)p * T_TOK * 3;

  __shared__ float AsT[8][128];
  __shared__ float Bs[8][128];
  __shared__ float gsh[128][3];

  const int tid = threadIdx.x;
  const int tx = tid & 15;
  const int ty = tid >> 4;
  const int row0 = blockIdx.x * 128;
  const int col0 = blockIdx.y * 128;

  for (int i = tid; i < 384; i += 256)
    gsh[i / 3][i % 3] = gbase[(size_t)(row0 + i / 3) * 3 + (i % 3)];

  float acc[8][8];
#pragma unroll
  for (int i = 0; i < 8; ++i)
#pragma unroll
    for (int j = 0; j < 8; ++j) acc[i][j] = 0.f;

  __syncthreads();

  const int ar = tid >> 1;
  const int ac = (tid & 1) << 2;
  const int br = tid >> 5;
  const int bc = (tid & 31) << 2;
  const float* xrow = x + (size_t)(row0 + ar) * E_DIM + ac;

  for (int kk = 0; kk < 3072; kk += 8) {
    const int n = kk >> 10;
    const int k = kk & 1023;
    const float g = gsh[ar][n];
    const float4 av = *(const float4*)(xrow + k);
    AsT[ac + 0][ar] = av.x * g;
    AsT[ac + 1][ar] = av.y * g;
    AsT[ac + 2][ar] = av.z * g;
    AsT[ac + 3][ar] = av.w * g;
    *(float4*)(&Bs[br][bc]) =
        *(const float4*)(W + (size_t)n * 1048576 + (size_t)(k + br) * 1024 + col0 + bc);
    __syncthreads();
#pragma unroll
    for (int kq = 0; kq < 8; ++kq) {
      const float4 a0 = *(const float4*)(&AsT[kq][ty * 4]);
      const float4 a1 = *(const float4*)(&AsT[kq][64 + ty * 4]);
      const float4 b0 = *(const float4*)(&Bs[kq][tx * 4]);
      const float4 b1 = *(const float4*)(&Bs[kq][64 + tx * 4]);
      const float a[8] = {a0.x, a0.y, a0.z, a0.w, a1.x, a1.y, a1.z, a1.w};
      const float b[8] = {b0.x, b0.y, b0.z, b0.w, b1.x, b1.y, b1.z, b1.w};
#pragma unroll
      for (int i = 0; i < 8; ++i)
#pragma unroll
        for (int j = 0; j < 8; ++j) acc[i][j] = fmaf(a[i], b[j], acc[i][j]);
    }
    __syncthreads();
  }

#pragma unroll
  for (int ih = 0; ih < 2; ++ih) {
#pragma unroll
    for (int i = 0; i < 4; ++i) {
      const int rl = ih * 64 + ty * 4 + i;
      const float g0 = gsh[rl][0], g1 = gsh[rl][1], g2 = gsh[rl][2];
      float* orow = out + (size_t)(row0 + rl) * E_DIM;
#pragma unroll
      for (int jh = 0; jh < 2; ++jh) {
        const int cl = jh * 64 + tx * 4;
        const int c = col0 + cl;
        float4 v;
        v.x = acc[ih * 4 + i][jh * 4 + 0] + g0 * bias[c + 0] + g1 * bias[1024 + c + 0] + g2 * bias[2048 + c + 0];
        v.y = acc[ih * 4 + i][jh * 4 + 1] + g0 * bias[c + 1] + g1 * bias[1024 + c + 1] + g2 * bias[2048 + c + 1];
        v.z = acc[ih * 4 + i][jh * 4 + 2] + g0 * bias[c + 2] + g1 * bias[1024 + c + 2] + g2 * bias[2048 + c + 2];
        v.w = acc[ih * 4 + i][jh * 4 + 3] + g0 * bias[c + 3] + g1 * bias[1024 + c + 3] + g2 * bias[2048 + c + 3];
        *(float4*)(orow + c) = v;
      }
    }
  }
}

// ---------------------------------------------------------------------------
// Kernel 3: flash attention, fp32 (unchanged this round).
// ---------------------------------------------------------------------------
__global__ __launch_bounds__(256) void attn_kernel(
    const float* __restrict__ xq, const float* __restrict__ xk,
    const float* __restrict__ xv, float* __restrict__ out) {
  __shared__ float QsT[64][64];
  __shared__ float KsT[64][64];
  __shared__ float Vs[64][64];
  __shared__ float Ss[64][65];
  __shared__ float mstate[64], lstate[64], alphas[64];

  const int tid = threadIdx.x;
  const int tx = tid & 15;
  const int ty = tid >> 4;
  const int qt0 = blockIdx.x * 64;
  const int mh = blockIdx.y;
  const int mi = mh >> 4, h = mh & 15;
  const size_t base = ((size_t)mi * S_LEN) * E_DIM + (size_t)h * 64;

  for (int it = tid; it < 1024; it += 256) {
    const int row = it >> 4, c4 = (it & 15) << 2;
    const float4 qv = *(const float4*)(xq + base + (size_t)(qt0 + row) * E_DIM + c4);
    QsT[c4 + 0][row] = qv.x;
    QsT[c4 + 1][row] = qv.y;
    QsT[c4 + 2][row] = qv.z;
    QsT[c4 + 3][row] = qv.w;
  }
  if (tid < 64) {
    mstate[tid] = -3.0e38f;
    lstate[tid] = 0.f;
  }
  float o[4][4];
#pragma unroll
  for (int i = 0; i < 4; ++i)
#pragma unroll
    for (int j = 0; j < 4; ++j) o[i][j] = 0.f;

  for (int jt = 0; jt < 32; ++jt) {
    __syncthreads();
    const int kt0 = jt * 64;
    for (int it = tid; it < 1024; it += 256) {
      const int row = it >> 4, c4 = (it & 15) << 2;
      const size_t ga = base + (size_t)(kt0 + row) * E_DIM + c4;
      const float4 kv = *(const float4*)(xk + ga);
      KsT[c4 + 0][row] = kv.x;
      KsT[c4 + 1][row] = kv.y;
      KsT[c4 + 2][row] = kv.z;
      KsT[c4 + 3][row] = kv.w;
      *(float4*)(&Vs[row][c4]) = *(const float4*)(xv + ga);
    }
    __syncthreads();

    float s[4][4];
#pragma unroll
    for (int i = 0; i < 4; ++i)
#pragma unroll
      for (int j = 0; j < 4; ++j) s[i][j] = 0.f;
#pragma unroll 8
    for (int d = 0; d < 64; ++d) {
      const float4 a4 = *(const float4*)(&QsT[d][ty * 4]);
      const float4 b4 = *(const float4*)(&KsT[d][tx * 4]);
      const float a[4] = {a4.x, a4.y, a4.z, a4.w};
      const float b[4] = {b4.x, b4.y, b4.z, b4.w};
#pragma unroll
      for (int i = 0; i < 4; ++i)
#pragma unroll
        for (int j = 0; j < 4; ++j) s[i][j] = fmaf(a[i], b[j], s[i][j]);
    }
#pragma unroll
    for (int i = 0; i < 4; ++i)
#pragma unroll
      for (int j = 0; j < 4; ++j) Ss[ty * 4 + i][tx * 4 + j] = s[i][j] * 0.125f;
    __syncthreads();

    {
      const int q = tid >> 2, part = tid & 3;
      const int k0 = part * 16;
      const float mprev = mstate[q];
      float mcur = -3.0e38f;
#pragma unroll
      for (int k2 = 0; k2 < 16; ++k2) mcur = fmaxf(mcur, Ss[q][k0 + k2]);
      mcur = fmaxf(mcur, __shfl_xor(mcur, 1, 64));
      mcur = fmaxf(mcur, __shfl_xor(mcur, 2, 64));
      const float mnew = fmaxf(mprev, mcur);
      float rs = 0.f;
#pragma unroll
      for (int k2 = 0; k2 < 16; ++k2) {
        const float pv = __expf(Ss[q][k0 + k2] - mnew);
        Ss[q][k0 + k2] = pv;
        rs += pv;
      }
      rs += __shfl_xor(rs, 1, 64);
      rs += __shfl_xor(rs, 2, 64);
      if (part == 0) {
        const float alpha = __expf(mprev - mnew);
        lstate[q] = lstate[q] * alpha + rs;
        mstate[q] = mnew;
        alphas[q] = alpha;
      }
    }
    __syncthreads();

    float al[4];
#pragma unroll
    for (int i = 0; i < 4; ++i) al[i] = alphas[ty * 4 + i];
#pragma unroll
    for (int i = 0; i < 4; ++i)
#pragma unroll
      for (int j = 0; j < 4; ++j) o[i][j] *= al[i];
#pragma unroll 8
    for (int k2 = 0; k2 < 64; ++k2) {
      float pr[4];
#pragma unroll
      for (int i = 0; i < 4; ++i) pr[i] = Ss[ty * 4 + i][k2];
      const float4 v4 = *(const float4*)(&Vs[k2][tx * 4]);
#pragma unroll
      for (int i = 0; i < 4; ++i) {
        o[i][0] = fmaf(pr[i], v4.x, o[i][0]);
        o[i][1] = fmaf(pr[i], v4.y, o[i][1]);
        o[i][2] = fmaf(pr[i], v4.z, o[i][2]);
        o[i][3] = fmaf(pr[i], v4.w, o[i][3]);
      }
    }
  }

#pragma unroll
  for (int i = 0; i < 4; ++i) {
    const float linv = 1.f / lstate[ty * 4 + i];
    float4 v;
    v.x = o[i][0] * linv;
    v.y = o[i][1] * linv;
    v.z = o[i][2] * linv;
    v.w = o[i][3] * linv;
    *(float4*)(out + base + (size_t)(qt0 + ty * 4 + i) * E_DIM + tx * 4) = v;
  }
}

// ---------------------------------------------------------------------------
extern "C" void kernel_launch(void* const* d_in, const int* in_sizes, int n_in,
                              void* d_out, int out_size, void* d_ws, size_t ws_size,
                              hipStream_t stream) {
  (void)in_sizes; (void)n_in; (void)out_size;
  const float* x   = (const float*)d_in[0];
  const float* Wq  = (const float*)d_in[1];
  const float* bq  = (const float*)d_in[2];
  const float* Wgq = (const float*)d_in[3];
  const float* bgq = (const float*)d_in[4];
  const float* Wk  = (const float*)d_in[5];
  const float* bk  = (const float*)d_in[6];
  const float* Wgk = (const float*)d_in[7];
  const float* bgk = (const float*)d_in[8];
  const float* Wv  = (const float*)d_in[9];
  const float* bv  = (const float*)d_in[10];
  const float* Wgv = (const float*)d_in[11];
  const float* bgv = (const float*)d_in[12];
  float* out = (float*)d_out;

  // layout: gates | xs_h | xs_l | wt_h | wt_l | xq | xk | xv
  const size_t off_xsh = 294912;
  const size_t off_xsl = off_xsh + 16777216;
  const size_t off_wth = off_xsl + 16777216;
  const size_t off_wtl = off_wth + 18874368;
  const size_t off_xq  = off_wtl + 18874368;   // 71,598,080
  const size_t need_mfma = off_xq + 3ull * 33554432;  // ~164 MiB
  const size_t need_f32  = 294912 + 3ull * 33554432;  // ~101 MiB (fallback)

  float* gates = (float*)d_ws;

  if (ws_size >= need_mfma) {
    _Float16* xsh = (_Float16*)((char*)d_ws + off_xsh);
    _Float16* xsl = (_Float16*)((char*)d_ws + off_xsl);
    _Float16* wth = (_Float16*)((char*)d_ws + off_wth);
    _Float16* wtl = (_Float16*)((char*)d_ws + off_wtl);
    float* xq = (float*)((char*)d_ws + off_xq);
    float* xk = xq + (size_t)T_TOK * E_DIM;
    float* xv = xk + (size_t)T_TOK * E_DIM;

    split_x_kernel<<<dim3(8192), dim3(256), 0, stream>>>(x, xsh, xsl);
    split_w_kernel<<<dim3(256, 9), dim3(256), 0, stream>>>(Wq, Wk, Wv, wth, wtl);
    gates_kernel<<<dim3(T_TOK), dim3(64), 0, stream>>>(x, Wgq, bgq, Wgk, bgk, Wgv, bgv, gates);
    moe_mfma_kernel<<<dim3(T_TOK / 128, E_DIM / 128, 3), dim3(256), 0, stream>>>(
        xsh, xsl, wth, wtl, bq, bk, bv, gates, xq, xk, xv);
    attn_kernel<<<dim3(S_LEN / 64, 64), dim3(256), 0, stream>>>(xq, xk, xv, out);
  } else if (ws_size >= need_f32) {
    float* xq = (float*)((char*)d_ws + 294912);
    float* xk = xq + (size_t)T_TOK * E_DIM;
    float* xv = xk + (size_t)T_TOK * E_DIM;
    gates_kernel<<<dim3(T_TOK), dim3(64), 0, stream>>>(x, Wgq, bgq, Wgk, bgk, Wgv, bgv, gates);
    moe_gemm_kernel<<<dim3(T_TOK / 128, E_DIM / 128, 3), dim3(256), 0, stream>>>(
        x, Wq, bq, Wk, bk, Wv, bv, gates, xq, xk, xv);
    attn_kernel<<<dim3(S_LEN / 64, 64), dim3(256), 0, stream>>>(xq, xk, xv, out);
  }
}

// Round 5
// 968.746 us; speedup vs baseline: 3.2189x; 1.9089x over previous
//
#include <hip/hip_runtime.h>
#include <math.h>

#define T_TOK 8192   // m*s = 4*2048 tokens
#define E_DIM 1024
#define S_LEN 2048

typedef _Float16 f16x4 __attribute__((ext_vector_type(4)));
typedef _Float16 f16x8 __attribute__((ext_vector_type(8)));
typedef float f32x16 __attribute__((ext_vector_type(16)));

// async global->LDS 16B: LDS dst is wave-uniform base + lane*16 (contiguous).
__device__ __forceinline__ void async16(const void* g, void* l) {
  __builtin_amdgcn_global_load_lds(
      (const __attribute__((address_space(1))) void*)g,
      (__attribute__((address_space(3))) void*)l, 16, 0, 0);
}

// ---------------------------------------------------------------------------
// Kernel 1: per-token gate softmax for all 3 projections.
// ---------------------------------------------------------------------------
__global__ __launch_bounds__(64) void gates_kernel(
    const float* __restrict__ x,
    const float* __restrict__ Wgq, const float* __restrict__ bgq,
    const float* __restrict__ Wgk, const float* __restrict__ bgk,
    const float* __restrict__ Wgv, const float* __restrict__ bgv,
    float* __restrict__ gates) {
  const int t = blockIdx.x;
  const int lane = threadIdx.x;
  const float* xr = x + (size_t)t * E_DIM;
  float acc[9];
#pragma unroll
  for (int i = 0; i < 9; ++i) acc[i] = 0.f;
  for (int e = lane; e < E_DIM; e += 64) {
    const float xv = xr[e];
    acc[0] = fmaf(xv, Wgq[e * 3 + 0], acc[0]);
    acc[1] = fmaf(xv, Wgq[e * 3 + 1], acc[1]);
    acc[2] = fmaf(xv, Wgq[e * 3 + 2], acc[2]);
    acc[3] = fmaf(xv, Wgk[e * 3 + 0], acc[3]);
    acc[4] = fmaf(xv, Wgk[e * 3 + 1], acc[4]);
    acc[5] = fmaf(xv, Wgk[e * 3 + 2], acc[5]);
    acc[6] = fmaf(xv, Wgv[e * 3 + 0], acc[6]);
    acc[7] = fmaf(xv, Wgv[e * 3 + 1], acc[7]);
    acc[8] = fmaf(xv, Wgv[e * 3 + 2], acc[8]);
  }
#pragma unroll
  for (int off = 32; off > 0; off >>= 1) {
#pragma unroll
    for (int i = 0; i < 9; ++i) acc[i] += __shfl_down(acc[i], off, 64);
  }
  if (lane == 0) {
    const float* bg[3] = {bgq, bgk, bgv};
#pragma unroll
    for (int p = 0; p < 3; ++p) {
      float z0 = acc[p * 3 + 0] + bg[p][0];
      float z1 = acc[p * 3 + 1] + bg[p][1];
      float z2 = acc[p * 3 + 2] + bg[p][2];
      float mx = fmaxf(z0, fmaxf(z1, z2));
      float e0 = expf(z0 - mx), e1 = expf(z1 - mx), e2 = expf(z2 - mx);
      float inv = 1.f / (e0 + e1 + e2);
      float* gp = gates + ((size_t)p * T_TOK + t) * 3;
      gp[0] = e0 * inv;
      gp[1] = e1 * inv;
      gp[2] = e2 * inv;
    }
  }
}

// ---------------------------------------------------------------------------
// Kernel P1: split x (fp32) -> xh + xl (f16 hi/lo), same [t][k] layout.
// ---------------------------------------------------------------------------
__global__ __launch_bounds__(256) void split_x_kernel(
    const float* __restrict__ x, _Float16* __restrict__ xh, _Float16* __restrict__ xl) {
  const size_t i = ((size_t)blockIdx.x * 256 + threadIdx.x) * 4;
  const float4 v = *(const float4*)(x + i);
  f16x4 h, lo;
  h[0] = (_Float16)v.x; lo[0] = (_Float16)(v.x - (float)h[0]);
  h[1] = (_Float16)v.y; lo[1] = (_Float16)(v.y - (float)h[1]);
  h[2] = (_Float16)v.z; lo[2] = (_Float16)(v.z - (float)h[2]);
  h[3] = (_Float16)v.w; lo[3] = (_Float16)(v.w - (float)h[3]);
  *(f16x4*)(xh + i) = h;
  *(f16x4*)(xl + i) = lo;
}

// ---------------------------------------------------------------------------
// Kernel P2: split + transpose W. Out: wh/wl[mat][c][k] f16 (k contiguous).
// ---------------------------------------------------------------------------
__global__ __launch_bounds__(256) void split_w_kernel(
    const float* __restrict__ Wq, const float* __restrict__ Wk, const float* __restrict__ Wv,
    _Float16* __restrict__ wh, _Float16* __restrict__ wl) {
  const int mat = blockIdx.y;
  const float* W = ((mat < 3) ? Wq : (mat < 6) ? Wk : Wv) + (size_t)(mat % 3) * 1048576;
  const int kt = (blockIdx.x >> 4) * 64, ct = (blockIdx.x & 15) * 64;
  __shared__ _Float16 hs[64][72];
  __shared__ _Float16 ls[64][72];
  const int tid = threadIdx.x;
#pragma unroll
  for (int i = 0; i < 4; ++i) {
    const int r = (tid >> 4) + i * 16;
    const int c4 = (tid & 15) * 4;
    const float4 v = *(const float4*)(W + (size_t)(kt + r) * 1024 + ct + c4);
    _Float16 h;
    h = (_Float16)v.x; hs[c4 + 0][r] = h; ls[c4 + 0][r] = (_Float16)(v.x - (float)h);
    h = (_Float16)v.y; hs[c4 + 1][r] = h; ls[c4 + 1][r] = (_Float16)(v.y - (float)h);
    h = (_Float16)v.z; hs[c4 + 2][r] = h; ls[c4 + 2][r] = (_Float16)(v.z - (float)h);
    h = (_Float16)v.w; hs[c4 + 3][r] = h; ls[c4 + 3][r] = (_Float16)(v.w - (float)h);
  }
  __syncthreads();
#pragma unroll
  for (int i = 0; i < 2; ++i) {
    const int u = tid + i * 256;
    const int c = u >> 3, seg = u & 7;
    const size_t o = (size_t)mat * 1048576 + (size_t)(ct + c) * 1024 + kt + seg * 8;
    *(f16x8*)(wh + o) = *(const f16x8*)(&hs[c][seg * 8]);
    *(f16x8*)(wl + o) = *(const f16x8*)(&ls[c][seg * 8]);
  }
}

// ---------------------------------------------------------------------------
// Kernel 2 (MFMA): MoE expert GEMM, f16 hi/lo 3-pass, 32x32x16 MFMA.
// ---------------------------------------------------------------------------
__global__ __launch_bounds__(256, 2) void moe_mfma_kernel(
    const _Float16* __restrict__ xh, const _Float16* __restrict__ xl,
    const _Float16* __restrict__ wh, const _Float16* __restrict__ wl,
    const float* __restrict__ bq_, const float* __restrict__ bk_, const float* __restrict__ bv_,
    const float* __restrict__ gates,
    float* __restrict__ oq_, float* __restrict__ ok_, float* __restrict__ ov_) {
  const int p = blockIdx.z;
  const float* bias = (p == 0) ? bq_ : (p == 1) ? bk_ : bv_;
  float* out = (p == 0) ? oq_ : (p == 1) ? ok_ : ov_;

  __shared__ _Float16 Ah[128][32], Al[128][32], Bh[128][32], Bl[128][32];
  __shared__ float gsh[128][3];
  __shared__ float bsh[3][128];

  const int tid = threadIdx.x;
  const int l = tid & 63, w = tid >> 6;
  const int wm = w & 1, wn = w >> 1;
  const int row0 = blockIdx.x * 128, col0 = blockIdx.y * 128;

  for (int i = tid; i < 384; i += 256)
    gsh[i / 3][i % 3] = gates[((size_t)p * T_TOK + row0 + i / 3) * 3 + (i % 3)];
  for (int i = tid; i < 384; i += 256)
    bsh[i >> 7][i & 127] = bias[(i >> 7) * 1024 + col0 + (i & 127)];

  const int m = l & 31, half = l >> 5;
  const int S = (m >> 1) & 3;
  const int rr = l >> 2;
  const int gc = (l & 3) ^ ((l >> 3) & 3);
  const size_t aoff = (size_t)(row0 + w * 32 + rr) * 1024 + gc * 8;

  f32x16 fin[2][2];
#pragma unroll
  for (int i = 0; i < 2; ++i)
#pragma unroll
    for (int j = 0; j < 2; ++j)
#pragma unroll
      for (int r = 0; r < 16; ++r) fin[i][j][r] = 0.f;

  for (int e = 0; e < 3; ++e) {
    f32x16 acc[2][2];
#pragma unroll
    for (int i = 0; i < 2; ++i)
#pragma unroll
      for (int j = 0; j < 2; ++j)
#pragma unroll
        for (int r = 0; r < 16; ++r) acc[i][j][r] = 0.f;

    const size_t wbase = ((size_t)(p * 3 + e) * 1024 + col0 + w * 32 + rr) * 1024 + gc * 8;

    for (int ks = 0; ks < 32; ++ks) {
      const int k0 = ks * 32;
      __syncthreads();
      async16(xh + aoff + k0,             &Ah[w * 32][0]);
      async16(xh + aoff + k0 + 16 * 1024, &Ah[w * 32 + 16][0]);
      async16(xl + aoff + k0,             &Al[w * 32][0]);
      async16(xl + aoff + k0 + 16 * 1024, &Al[w * 32 + 16][0]);
      async16(wh + wbase + k0,             &Bh[w * 32][0]);
      async16(wh + wbase + k0 + 16 * 1024, &Bh[w * 32 + 16][0]);
      async16(wl + wbase + k0,             &Bl[w * 32][0]);
      async16(wl + wbase + k0 + 16 * 1024, &Bl[w * 32 + 16][0]);
      __syncthreads();

#pragma unroll
      for (int ss = 0; ss < 2; ++ss) {
        const int ch = ((ss << 1) | half) ^ S;
        f16x8 a_h[2], a_l[2], b_h[2], b_l[2];
#pragma unroll
        for (int i = 0; i < 2; ++i) {
          const int rA = wm * 64 + i * 32 + m;
          a_h[i] = *(const f16x8*)(&Ah[rA][ch * 8]);
          a_l[i] = *(const f16x8*)(&Al[rA][ch * 8]);
          const int rB = wn * 64 + i * 32 + m;
          b_h[i] = *(const f16x8*)(&Bh[rB][ch * 8]);
          b_l[i] = *(const f16x8*)(&Bl[rB][ch * 8]);
        }
#pragma unroll
        for (int i = 0; i < 2; ++i)
#pragma unroll
          for (int j = 0; j < 2; ++j) {
            acc[i][j] = __builtin_amdgcn_mfma_f32_32x32x16_f16(a_h[i], b_h[j], acc[i][j], 0, 0, 0);
            acc[i][j] = __builtin_amdgcn_mfma_f32_32x32x16_f16(a_h[i], b_l[j], acc[i][j], 0, 0, 0);
            acc[i][j] = __builtin_amdgcn_mfma_f32_32x32x16_f16(a_l[i], b_h[j], acc[i][j], 0, 0, 0);
          }
      }
    }
#pragma unroll
    for (int i = 0; i < 2; ++i)
#pragma unroll
      for (int r = 0; r < 16; ++r) {
        const int row_l = wm * 64 + i * 32 + (r & 3) + ((r >> 2) << 3) + (half << 2);
        const float g = gsh[row_l][e];
#pragma unroll
        for (int j = 0; j < 2; ++j) fin[i][j][r] += g * acc[i][j][r];
      }
  }

#pragma unroll
  for (int j = 0; j < 2; ++j) {
    const int col_l = wn * 64 + j * 32 + m;
    const float b0 = bsh[0][col_l], b1 = bsh[1][col_l], b2 = bsh[2][col_l];
#pragma unroll
    for (int i = 0; i < 2; ++i)
#pragma unroll
      for (int r = 0; r < 16; ++r) {
        const int row_l = wm * 64 + i * 32 + (r & 3) + ((r >> 2) << 3) + (half << 2);
        const float g0 = gsh[row_l][0], g1 = gsh[row_l][1], g2 = gsh[row_l][2];
        out[(size_t)(row0 + row_l) * 1024 + col0 + col_l] =
            fin[i][j][r] + g0 * b0 + g1 * b1 + g2 * b2;
      }
  }
}

// ---------------------------------------------------------------------------
// Kernel P3: repack f32 [t][e] -> chunk-swizzled f16 hi/lo [t][e'].
// Swizzle: within each head's 64 d, chunk c (of 8) stored at c ^ (t&7).
// scale folded (0.125 for Q). grid 8192 x 256.
// ---------------------------------------------------------------------------
__global__ __launch_bounds__(256) void repack_qk_kernel(
    const float* __restrict__ src, _Float16* __restrict__ h, _Float16* __restrict__ lo,
    float scale) {
  const size_t i = ((size_t)blockIdx.x * 256 + threadIdx.x) * 4;
  float4 v = *(const float4*)(src + i);
  v.x *= scale; v.y *= scale; v.z *= scale; v.w *= scale;
  const int t = (int)(i >> 10);
  const int e = (int)(i & 1023);
  const int d = e & 63, c = d >> 3, j = d & 7;  // j in {0,4}
  const size_t dst = (i & ~(size_t)63) + (size_t)(((c ^ (t & 7)) << 3) | j);
  f16x4 hh, ll;
  hh[0] = (_Float16)v.x; ll[0] = (_Float16)(v.x - (float)hh[0]);
  hh[1] = (_Float16)v.y; ll[1] = (_Float16)(v.y - (float)hh[1]);
  hh[2] = (_Float16)v.z; ll[2] = (_Float16)(v.z - (float)hh[2]);
  hh[3] = (_Float16)v.w; ll[3] = (_Float16)(v.w - (float)hh[3]);
  *(f16x4*)(h + dst) = hh;
  *(f16x4*)(lo + dst) = ll;
}

// ---------------------------------------------------------------------------
// Kernel P4: transpose V -> vT[(mi*16+h)*64 + d][2048 s] f16 hi/lo,
// chunk-swizzled within each 64-aligned s-tile: chunk kc at kc ^ (d&7).
// ---------------------------------------------------------------------------
__global__ __launch_bounds__(256) void repack_vT_kernel(
    const float* __restrict__ xv, _Float16* __restrict__ vth, _Float16* __restrict__ vtl) {
  const int mh = blockIdx.y;
  const int s0 = blockIdx.x * 64;
  __shared__ _Float16 hs[64][72];  // [d][s]
  __shared__ _Float16 ls[64][72];
  const int tid = threadIdx.x;
#pragma unroll
  for (int i = 0; i < 4; ++i) {
    const int idx = tid + i * 256;
    const int sr = idx >> 4;
    const int c4 = (idx & 15) * 4;
    const float4 v = *(const float4*)(
        xv + ((size_t)(mh >> 4) * S_LEN + s0 + sr) * 1024 + (mh & 15) * 64 + c4);
    _Float16 h;
    h = (_Float16)v.x; hs[c4 + 0][sr] = h; ls[c4 + 0][sr] = (_Float16)(v.x - (float)h);
    h = (_Float16)v.y; hs[c4 + 1][sr] = h; ls[c4 + 1][sr] = (_Float16)(v.y - (float)h);
    h = (_Float16)v.z; hs[c4 + 2][sr] = h; ls[c4 + 2][sr] = (_Float16)(v.z - (float)h);
    h = (_Float16)v.w; hs[c4 + 3][sr] = h; ls[c4 + 3][sr] = (_Float16)(v.w - (float)h);
  }
  __syncthreads();
#pragma unroll
  for (int i = 0; i < 2; ++i) {
    const int u = tid + i * 256;
    const int d = u >> 3, kc = u & 7;
    const int phys = kc ^ (d & 7);
    const size_t o = ((size_t)mh * 64 + d) * (size_t)S_LEN + s0 + phys * 8;
    *(f16x8*)(vth + o) = *(const f16x8*)(&hs[d][kc * 8]);
    *(f16x8*)(vtl + o) = *(const f16x8*)(&ls[d][kc * 8]);
  }
}

// ---------------------------------------------------------------------------
// Kernel 3 (MFMA): flash attention, f16 hi/lo 3-pass.
// Block = (64-q-tile, head). FIXED vs R4: Q/K global staging now includes the
// batch offset mi*S_LEN (R4 read batch 0's Q/K for all batches).
// ---------------------------------------------------------------------------
__global__ __launch_bounds__(256, 3) void attn_mfma_kernel(
    const _Float16* __restrict__ qh, const _Float16* __restrict__ ql,
    const _Float16* __restrict__ kh, const _Float16* __restrict__ kl,
    const _Float16* __restrict__ vth, const _Float16* __restrict__ vtl,
    float* __restrict__ out) {
  __shared__ __align__(16) char KSraw[16640];   // Kh | Kl ; overlaid: S f32 stride 65
  __shared__ __align__(16) char QPraw[16384];   // Qh | Ql ; overlaid: Ph | Pl
  __shared__ __align__(16) char VTraw[16384];   // VTh | VTl
  __shared__ float alphas[64];
  __shared__ float lstate[64];

  _Float16* Kh = (_Float16*)KSraw;
  _Float16* Kl = Kh + 4096;
  float* Sb = (float*)KSraw;          // [64][65]
  _Float16* Qh = (_Float16*)QPraw;    // == Ph
  _Float16* Ql = Qh + 4096;           // == Pl
  _Float16* VTh = (_Float16*)VTraw;
  _Float16* VTl = VTh + 4096;

  const int tid = threadIdx.x;
  const int l = tid & 63, w = tid >> 6;
  const int wm = w & 1, wn = w >> 1;
  const int m = l & 31, half = l >> 5;
  const int key = m & 7;
  const int qt0 = blockIdx.x * 64;
  const int mh = blockIdx.y;          // mi*16 + h
  const int mi = mh >> 4, h = mh & 15;
  const size_t tok0 = (size_t)mi * S_LEN;   // batch token offset (THE FIX)

  // staging lane constants
  const int r8 = l >> 3, c8 = l & 7;

  // ---- stage Q (once) ----
  {
    const size_t g0 = (tok0 + qt0 + w * 16 + r8) * 1024 + h * 64 + c8 * 8;
    async16(qh + g0,            Qh + (w * 16) * 64);
    async16(qh + g0 + 8 * 1024, Qh + (w * 16 + 8) * 64);
    async16(ql + g0,            Ql + (w * 16) * 64);
    async16(ql + g0 + 8 * 1024, Ql + (w * 16 + 8) * 64);
  }
  __syncthreads();

  // ---- preload Q fragments into registers ----
  f16x8 qa_h[4], qa_l[4];
#pragma unroll
  for (int ks = 0; ks < 4; ++ks) {
    const int phys = (ks * 2 + half) ^ key;
    const int ro = (wm * 32 + m) * 64 + phys * 8;
    qa_h[ks] = *(const f16x8*)(Qh + ro);
    qa_l[ks] = *(const f16x8*)(Ql + ro);
  }

  const int sq = tid >> 2, part = tid & 3;  // softmax: 4 lanes per q-row
  const int k0 = part * 16;
  float mreg = -3.0e38f, lreg = 0.f;

  f32x16 o_acc;
#pragma unroll
  for (int r = 0; r < 16; ++r) o_acc[r] = 0.f;

  for (int jt = 0; jt < 32; ++jt) {
    const int kt0 = jt * 64;
    __syncthreads();  // prior iter's K/VT/P/S consumers done (also drains Q preload reads)

    // ---- stage K and VT ----
    {
      const size_t g0 = (tok0 + kt0 + w * 16 + r8) * 1024 + h * 64 + c8 * 8;
      async16(kh + g0,            Kh + (w * 16) * 64);
      async16(kh + g0 + 8 * 1024, Kh + (w * 16 + 8) * 64);
      async16(kl + g0,            Kl + (w * 16) * 64);
      async16(kl + g0 + 8 * 1024, Kl + (w * 16 + 8) * 64);
      const size_t v0 = ((size_t)mh * 64 + w * 16 + r8) * (size_t)S_LEN + kt0 + c8 * 8;
      async16(vth + v0,            VTh + (w * 16) * 64);
      async16(vth + v0 + 8 * 2048, VTh + (w * 16 + 8) * 64);
      async16(vtl + v0,            VTl + (w * 16) * 64);
      async16(vtl + v0 + 8 * 2048, VTl + (w * 16 + 8) * 64);
    }
    __syncthreads();

    // ---- QK^T (3-pass hi/lo) ----
    f32x16 s_acc;
#pragma unroll
    for (int r = 0; r < 16; ++r) s_acc[r] = 0.f;
#pragma unroll
    for (int ks = 0; ks < 4; ++ks) {
      const int phys = (ks * 2 + half) ^ key;
      const int bo = (wn * 32 + m) * 64 + phys * 8;
      const f16x8 kb_h = *(const f16x8*)(Kh + bo);
      const f16x8 kb_l = *(const f16x8*)(Kl + bo);
      s_acc = __builtin_amdgcn_mfma_f32_32x32x16_f16(qa_h[ks], kb_h, s_acc, 0, 0, 0);
      s_acc = __builtin_amdgcn_mfma_f32_32x32x16_f16(qa_h[ks], kb_l, s_acc, 0, 0, 0);
      s_acc = __builtin_amdgcn_mfma_f32_32x32x16_f16(qa_l[ks], kb_h, s_acc, 0, 0, 0);
    }
    __syncthreads();  // all K frag reads done -> S may overwrite K region

    // ---- write S (f32, stride 65: conflict-free) ----
#pragma unroll
    for (int r = 0; r < 16; ++r) {
      const int row = wm * 32 + (r & 3) + ((r >> 2) << 3) + (half << 2);
      Sb[row * 65 + wn * 32 + m] = s_acc[r];
    }
    __syncthreads();

    // ---- online softmax (row sq, k-segment part*16..+15) ----
    {
      float pv[16];
      float mc = -3.0e38f;
#pragma unroll
      for (int k2 = 0; k2 < 16; ++k2) {
        pv[k2] = Sb[sq * 65 + k0 + k2];
        mc = fmaxf(mc, pv[k2]);
      }
      mc = fmaxf(mc, __shfl_xor(mc, 1, 64));
      mc = fmaxf(mc, __shfl_xor(mc, 2, 64));
      const float mn = fmaxf(mreg, mc);
      float rs = 0.f;
#pragma unroll
      for (int k2 = 0; k2 < 16; ++k2) {
        const float pe = __expf(pv[k2] - mn);
        pv[k2] = pe;
        rs += pe;
      }
      rs += __shfl_xor(rs, 1, 64);
      rs += __shfl_xor(rs, 2, 64);
      const float al = __expf(mreg - mn);
      lreg = lreg * al + rs;
      mreg = mn;
      if (part == 0) alphas[sq] = al;
      // pack P -> f16 hi/lo, chunk-swizzled rows (key sq&7)
      const int skey = sq & 7;
      f16x8 p_h, p_l;
#pragma unroll
      for (int z = 0; z < 8; ++z) {
        p_h[z] = (_Float16)pv[z];
        p_l[z] = (_Float16)(pv[z] - (float)p_h[z]);
      }
      int phys = (2 * part) ^ skey;
      *(f16x8*)(Qh + sq * 64 + phys * 8) = p_h;   // Ph
      *(f16x8*)(Ql + sq * 64 + phys * 8) = p_l;   // Pl
#pragma unroll
      for (int z = 0; z < 8; ++z) {
        p_h[z] = (_Float16)pv[8 + z];
        p_l[z] = (_Float16)(pv[8 + z] - (float)p_h[z]);
      }
      phys = (2 * part + 1) ^ skey;
      *(f16x8*)(Qh + sq * 64 + phys * 8) = p_h;
      *(f16x8*)(Ql + sq * 64 + phys * 8) = p_l;
    }
    __syncthreads();

    // ---- O = O*alpha + P·V (3-pass hi/lo) ----
#pragma unroll
    for (int r = 0; r < 16; ++r) {
      const int row = wm * 32 + (r & 3) + ((r >> 2) << 3) + (half << 2);
      o_acc[r] *= alphas[row];
    }
#pragma unroll
    for (int ks = 0; ks < 4; ++ks) {
      const int phys = (ks * 2 + half) ^ key;
      const int po = (wm * 32 + m) * 64 + phys * 8;
      const f16x8 pa_h = *(const f16x8*)(Qh + po);
      const f16x8 pa_l = *(const f16x8*)(Ql + po);
      const int vo = (wn * 32 + m) * 64 + phys * 8;
      const f16x8 vb_h = *(const f16x8*)(VTh + vo);
      const f16x8 vb_l = *(const f16x8*)(VTl + vo);
      o_acc = __builtin_amdgcn_mfma_f32_32x32x16_f16(pa_h, vb_h, o_acc, 0, 0, 0);
      o_acc = __builtin_amdgcn_mfma_f32_32x32x16_f16(pa_h, vb_l, o_acc, 0, 0, 0);
      o_acc = __builtin_amdgcn_mfma_f32_32x32x16_f16(pa_l, vb_h, o_acc, 0, 0, 0);
    }
  }

  // ---- epilogue ----
  if (part == 0) lstate[sq] = lreg;
  __syncthreads();
#pragma unroll
  for (int r = 0; r < 16; ++r) {
    const int row = wm * 32 + (r & 3) + ((r >> 2) << 3) + (half << 2);
    const float linv = 1.f / lstate[row];
    out[(tok0 + qt0 + row) * 1024 + h * 64 + wn * 32 + m] = o_acc[r] * linv;
  }
}

// ---------------------------------------------------------------------------
// Fallback kernels (fp32), used only if ws_size too small.
// ---------------------------------------------------------------------------
__global__ __launch_bounds__(256) void moe_gemm_kernel(
    const float* __restrict__ x,
    const float* __restrict__ Wq_, const float* __restrict__ bq_,
    const float* __restrict__ Wk_, const float* __restrict__ bk_,
    const float* __restrict__ Wv_, const float* __restrict__ bv_,
    const float* __restrict__ gates,
    float* __restrict__ oq_, float* __restrict__ ok_, float* __restrict__ ov_) {
  const int p = blockIdx.z;
  const float* W = (p == 0) ? Wq_ : (p == 1) ? Wk_ : Wv_;
  const float* bias = (p == 0) ? bq_ : (p == 1) ? bk_ : bv_;
  float* out = (p == 0) ? oq_ : (p == 1) ? ok_ : ov_;
  const float* gbase = gates + (size_t)p * T_TOK * 3;

  __shared__ float AsT[8][128];
  __shared__ float Bs[8][128];
  __shared__ float gsh[128][3];

  const int tid = threadIdx.x;
  const int tx = tid & 15;
  const int ty = tid >> 4;
  const int row0 = blockIdx.x * 128;
  const int col0 = blockIdx.y * 128;

  for (int i = tid; i < 384; i += 256)
    gsh[i / 3][i % 3] = gbase[(size_t)(row0 + i / 3) * 3 + (i % 3)];

  float acc[8][8];
#pragma unroll
  for (int i = 0; i < 8; ++i)
#pragma unroll
    for (int j = 0; j < 8; ++j) acc[i][j] = 0.f;

  __syncthreads();

  const int ar = tid >> 1;
  const int ac = (tid & 1) << 2;
  const int br = tid >> 5;
  const int bc = (tid & 31) << 2;
  const float* xrow = x + (size_t)(row0 + ar) * E_DIM + ac;

  for (int kk = 0; kk < 3072; kk += 8) {
    const int n = kk >> 10;
    const int k = kk & 1023;
    const float g = gsh[ar][n];
    const float4 av = *(const float4*)(xrow + k);
    AsT[ac + 0][ar] = av.x * g;
    AsT[ac + 1][ar] = av.y * g;
    AsT[ac + 2][ar] = av.z * g;
    AsT[ac + 3][ar] = av.w * g;
    *(float4*)(&Bs[br][bc]) =
        *(const float4*)(W + (size_t)n * 1048576 + (size_t)(k + br) * 1024 + col0 + bc);
    __syncthreads();
#pragma unroll
    for (int kq = 0; kq < 8; ++kq) {
      const float4 a0 = *(const float4*)(&AsT[kq][ty * 4]);
      const float4 a1 = *(const float4*)(&AsT[kq][64 + ty * 4]);
      const float4 b0 = *(const float4*)(&Bs[kq][tx * 4]);
      const float4 b1 = *(const float4*)(&Bs[kq][64 + tx * 4]);
      const float a[8] = {a0.x, a0.y, a0.z, a0.w, a1.x, a1.y, a1.z, a1.w};
      const float b[8] = {b0.x, b0.y, b0.z, b0.w, b1.x, b1.y, b1.z, b1.w};
#pragma unroll
      for (int i = 0; i < 8; ++i)
#pragma unroll
        for (int j = 0; j < 8; ++j) acc[i][j] = fmaf(a[i], b[j], acc[i][j]);
    }
    __syncthreads();
  }

#pragma unroll
  for (int ih = 0; ih < 2; ++ih) {
#pragma unroll
    for (int i = 0; i < 4; ++i) {
      const int rl = ih * 64 + ty * 4 + i;
      const float g0 = gsh[rl][0], g1 = gsh[rl][1], g2 = gsh[rl][2];
      float* orow = out + (size_t)(row0 + rl) * E_DIM;
#pragma unroll
      for (int jh = 0; jh < 2; ++jh) {
        const int cl = jh * 64 + tx * 4;
        const int c = col0 + cl;
        float4 v;
        v.x = acc[ih * 4 + i][jh * 4 + 0] + g0 * bias[c + 0] + g1 * bias[1024 + c + 0] + g2 * bias[2048 + c + 0];
        v.y = acc[ih * 4 + i][jh * 4 + 1] + g0 * bias[c + 1] + g1 * bias[1024 + c + 1] + g2 * bias[2048 + c + 1];
        v.z = acc[ih * 4 + i][jh * 4 + 2] + g0 * bias[c + 2] + g1 * bias[1024 + c + 2] + g2 * bias[2048 + c + 2];
        v.w = acc[ih * 4 + i][jh * 4 + 3] + g0 * bias[c + 3] + g1 * bias[1024 + c + 3] + g2 * bias[2048 + c + 3];
        *(float4*)(orow + c) = v;
      }
    }
  }
}

__global__ __launch_bounds__(256) void attn_kernel(
    const float* __restrict__ xq, const float* __restrict__ xk,
    const float* __restrict__ xv, float* __restrict__ out) {
  __shared__ float QsT[64][64];
  __shared__ float KsT[64][64];
  __shared__ float Vs[64][64];
  __shared__ float Ss[64][65];
  __shared__ float mstate[64], lstate[64], alphas[64];

  const int tid = threadIdx.x;
  const int tx = tid & 15;
  const int ty = tid >> 4;
  const int qt0 = blockIdx.x * 64;
  const int mh = blockIdx.y;
  const int mi = mh >> 4, h = mh & 15;
  const size_t base = ((size_t)mi * S_LEN) * E_DIM + (size_t)h * 64;

  for (int it = tid; it < 1024; it += 256) {
    const int row = it >> 4, c4 = (it & 15) << 2;
    const float4 qv = *(const float4*)(xq + base + (size_t)(qt0 + row) * E_DIM + c4);
    QsT[c4 + 0][row] = qv.x;
    QsT[c4 + 1][row] = qv.y;
    QsT[c4 + 2][row] = qv.z;
    QsT[c4 + 3][row] = qv.w;
  }
  if (tid < 64) {
    mstate[tid] = -3.0e38f;
    lstate[tid] = 0.f;
  }
  float o[4][4];
#pragma unroll
  for (int i = 0; i < 4; ++i)
#pragma unroll
    for (int j = 0; j < 4; ++j) o[i][j] = 0.f;

  for (int jt = 0; jt < 32; ++jt) {
    __syncthreads();
    const int kt0 = jt * 64;
    for (int it = tid; it < 1024; it += 256) {
      const int row = it >> 4, c4 = (it & 15) << 2;
      const size_t ga = base + (size_t)(kt0 + row) * E_DIM + c4;
      const float4 kv = *(const float4*)(xk + ga);
      KsT[c4 + 0][row] = kv.x;
      KsT[c4 + 1][row] = kv.y;
      KsT[c4 + 2][row] = kv.z;
      KsT[c4 + 3][row] = kv.w;
      *(float4*)(&Vs[row][c4]) = *(const float4*)(xv + ga);
    }
    __syncthreads();

    float s[4][4];
#pragma unroll
    for (int i = 0; i < 4; ++i)
#pragma unroll
      for (int j = 0; j < 4; ++j) s[i][j] = 0.f;
#pragma unroll 8
    for (int d = 0; d < 64; ++d) {
      const float4 a4 = *(const float4*)(&QsT[d][ty * 4]);
      const float4 b4 = *(const float4*)(&KsT[d][tx * 4]);
      const float a[4] = {a4.x, a4.y, a4.z, a4.w};
      const float b[4] = {b4.x, b4.y, b4.z, b4.w};
#pragma unroll
      for (int i = 0; i < 4; ++i)
#pragma unroll
        for (int j = 0; j < 4; ++j) s[i][j] = fmaf(a[i], b[j], s[i][j]);
    }
#pragma unroll
    for (int i = 0; i < 4; ++i)
#pragma unroll
      for (int j = 0; j < 4; ++j) Ss[ty * 4 + i][tx * 4 + j] = s[i][j] * 0.125f;
    __syncthreads();

    {
      const int q = tid >> 2, part = tid & 3;
      const int k0 = part * 16;
      const float mprev = mstate[q];
      float mcur = -3.0e38f;
#pragma unroll
      for (int k2 = 0; k2 < 16; ++k2) mcur = fmaxf(mcur, Ss[q][k0 + k2]);
      mcur = fmaxf(mcur, __shfl_xor(mcur, 1, 64));
      mcur = fmaxf(mcur, __shfl_xor(mcur, 2, 64));
      const float mnew = fmaxf(mprev, mcur);
      float rs = 0.f;
#pragma unroll
      for (int k2 = 0; k2 < 16; ++k2) {
        const float pv = __expf(Ss[q][k0 + k2] - mnew);
        Ss[q][k0 + k2] = pv;
        rs += pv;
      }
      rs += __shfl_xor(rs, 1, 64);
      rs += __shfl_xor(rs, 2, 64);
      if (part == 0) {
        const float alpha = __expf(mprev - mnew);
        lstate[q] = lstate[q] * alpha + rs;
        mstate[q] = mnew;
        alphas[q] = alpha;
      }
    }
    __syncthreads();

    float al[4];
#pragma unroll
    for (int i = 0; i < 4; ++i) al[i] = alphas[ty * 4 + i];
#pragma unroll
    for (int i = 0; i < 4; ++i)
#pragma unroll
      for (int j = 0; j < 4; ++j) o[i][j] *= al[i];
#pragma unroll 8
    for (int k2 = 0; k2 < 64; ++k2) {
      float pr[4];
#pragma unroll
      for (int i = 0; i < 4; ++i) pr[i] = Ss[ty * 4 + i][k2];
      const float4 v4 = *(const float4*)(&Vs[k2][tx * 4]);
#pragma unroll
      for (int i = 0; i < 4; ++i) {
        o[i][0] = fmaf(pr[i], v4.x, o[i][0]);
        o[i][1] = fmaf(pr[i], v4.y, o[i][1]);
        o[i][2] = fmaf(pr[i], v4.z, o[i][2]);
        o[i][3] = fmaf(pr[i], v4.w, o[i][3]);
      }
    }
  }

#pragma unroll
  for (int i = 0; i < 4; ++i) {
    const float linv = 1.f / lstate[ty * 4 + i];
    float4 v;
    v.x = o[i][0] * linv;
    v.y = o[i][1] * linv;
    v.z = o[i][2] * linv;
    v.w = o[i][3] * linv;
    *(float4*)(out + base + (size_t)(qt0 + ty * 4 + i) * E_DIM + tx * 4) = v;
  }
}

// ---------------------------------------------------------------------------
extern "C" void kernel_launch(void* const* d_in, const int* in_sizes, int n_in,
                              void* d_out, int out_size, void* d_ws, size_t ws_size,
                              hipStream_t stream) {
  (void)in_sizes; (void)n_in; (void)out_size;
  const float* x   = (const float*)d_in[0];
  const float* Wq  = (const float*)d_in[1];
  const float* bq  = (const float*)d_in[2];
  const float* Wgq = (const float*)d_in[3];
  const float* bgq = (const float*)d_in[4];
  const float* Wk  = (const float*)d_in[5];
  const float* bk  = (const float*)d_in[6];
  const float* Wgk = (const float*)d_in[7];
  const float* bgk = (const float*)d_in[8];
  const float* Wv  = (const float*)d_in[9];
  const float* bv  = (const float*)d_in[10];
  const float* Wgv = (const float*)d_in[11];
  const float* bgv = (const float*)d_in[12];
  float* out = (float*)d_out;

  // layout: gates | xs_h | xs_l | wt_h | wt_l | xq | xk | xv
  // lifetime overlays (stream-ordered): qh<-xs_h, ql<-xs_l, kh<-wt_h,
  // kl<-wt_l (dead after moe); vth/vtl <- xq region (dead after repack_q).
  const size_t off_xsh = 294912;
  const size_t off_xsl = off_xsh + 16777216;
  const size_t off_wth = off_xsl + 16777216;
  const size_t off_wtl = off_wth + 18874368;
  const size_t off_xq  = off_wtl + 18874368;
  const size_t need_mfma = off_xq + 3ull * 33554432;  // ~164 MiB
  const size_t need_f32  = 294912 + 3ull * 33554432;  // ~101 MiB (fallback)

  float* gates = (float*)d_ws;

  if (ws_size >= need_mfma) {
    _Float16* xsh = (_Float16*)((char*)d_ws + off_xsh);
    _Float16* xsl = (_Float16*)((char*)d_ws + off_xsl);
    _Float16* wth = (_Float16*)((char*)d_ws + off_wth);
    _Float16* wtl = (_Float16*)((char*)d_ws + off_wtl);
    float* xq = (float*)((char*)d_ws + off_xq);
    float* xk = xq + (size_t)T_TOK * E_DIM;
    float* xv = xk + (size_t)T_TOK * E_DIM;
    // overlays
    _Float16* qh  = xsh;
    _Float16* ql  = xsl;
    _Float16* khb = wth;
    _Float16* klb = wtl;
    _Float16* vth = (_Float16*)((char*)d_ws + off_xq);
    _Float16* vtl = vth + 8388608;

    split_x_kernel<<<dim3(8192), dim3(256), 0, stream>>>(x, xsh, xsl);
    split_w_kernel<<<dim3(256, 9), dim3(256), 0, stream>>>(Wq, Wk, Wv, wth, wtl);
    gates_kernel<<<dim3(T_TOK), dim3(64), 0, stream>>>(x, Wgq, bgq, Wgk, bgk, Wgv, bgv, gates);
    moe_mfma_kernel<<<dim3(T_TOK / 128, E_DIM / 128, 3), dim3(256), 0, stream>>>(
        xsh, xsl, wth, wtl, bq, bk, bv, gates, xq, xk, xv);
    repack_qk_kernel<<<dim3(8192), dim3(256), 0, stream>>>(xq, qh, ql, 0.125f);
    repack_qk_kernel<<<dim3(8192), dim3(256), 0, stream>>>(xk, khb, klb, 1.0f);
    repack_vT_kernel<<<dim3(32, 64), dim3(256), 0, stream>>>(xv, vth, vtl);
    attn_mfma_kernel<<<dim3(32, 64), dim3(256), 0, stream>>>(qh, ql, khb, klb, vth, vtl, out);
  } else if (ws_size >= need_f32) {
    float* xq = (float*)((char*)d_ws + 294912);
    float* xk = xq + (size_t)T_TOK * E_DIM;
    float* xv = xk + (size_t)T_TOK * E_DIM;
    gates_kernel<<<dim3(T_TOK), dim3(64), 0, stream>>>(x, Wgq, bgq, Wgk, bgk, Wgv, bgv, gates);
    moe_gemm_kernel<<<dim3(T_TOK / 128, E_DIM / 128, 3), dim3(256), 0, stream>>>(
        x, Wq, bq, Wk, bk, Wv, bv, gates, xq, xk, xv);
    attn_kernel<<<dim3(S_LEN / 64, 64), dim3(256), 0, stream>>>(xq, xk, xv, out);
  }
}

// Round 6
// 951.924 us; speedup vs baseline: 3.2758x; 1.0177x over previous
//
#include <hip/hip_runtime.h>
#include <math.h>

#define T_TOK 8192   // m*s = 4*2048 tokens
#define E_DIM 1024
#define S_LEN 2048

typedef _Float16 f16x4 __attribute__((ext_vector_type(4)));
typedef _Float16 f16x8 __attribute__((ext_vector_type(8)));
typedef float f32x16 __attribute__((ext_vector_type(16)));

// async global->LDS 16B: LDS dst is wave-uniform base + lane*16 (contiguous).
__device__ __forceinline__ void async16(const void* g, void* l) {
  __builtin_amdgcn_global_load_lds(
      (const __attribute__((address_space(1))) void*)g,
      (__attribute__((address_space(3))) void*)l, 16, 0, 0);
}

// ---------------------------------------------------------------------------
// Kernel 1: per-token gate softmax for all 3 projections.
// ---------------------------------------------------------------------------
__global__ __launch_bounds__(64) void gates_kernel(
    const float* __restrict__ x,
    const float* __restrict__ Wgq, const float* __restrict__ bgq,
    const float* __restrict__ Wgk, const float* __restrict__ bgk,
    const float* __restrict__ Wgv, const float* __restrict__ bgv,
    float* __restrict__ gates) {
  const int t = blockIdx.x;
  const int lane = threadIdx.x;
  const float* xr = x + (size_t)t * E_DIM;
  float acc[9];
#pragma unroll
  for (int i = 0; i < 9; ++i) acc[i] = 0.f;
  for (int e = lane; e < E_DIM; e += 64) {
    const float xv = xr[e];
    acc[0] = fmaf(xv, Wgq[e * 3 + 0], acc[0]);
    acc[1] = fmaf(xv, Wgq[e * 3 + 1], acc[1]);
    acc[2] = fmaf(xv, Wgq[e * 3 + 2], acc[2]);
    acc[3] = fmaf(xv, Wgk[e * 3 + 0], acc[3]);
    acc[4] = fmaf(xv, Wgk[e * 3 + 1], acc[4]);
    acc[5] = fmaf(xv, Wgk[e * 3 + 2], acc[5]);
    acc[6] = fmaf(xv, Wgv[e * 3 + 0], acc[6]);
    acc[7] = fmaf(xv, Wgv[e * 3 + 1], acc[7]);
    acc[8] = fmaf(xv, Wgv[e * 3 + 2], acc[8]);
  }
#pragma unroll
  for (int off = 32; off > 0; off >>= 1) {
#pragma unroll
    for (int i = 0; i < 9; ++i) acc[i] += __shfl_down(acc[i], off, 64);
  }
  if (lane == 0) {
    const float* bg[3] = {bgq, bgk, bgv};
#pragma unroll
    for (int p = 0; p < 3; ++p) {
      float z0 = acc[p * 3 + 0] + bg[p][0];
      float z1 = acc[p * 3 + 1] + bg[p][1];
      float z2 = acc[p * 3 + 2] + bg[p][2];
      float mx = fmaxf(z0, fmaxf(z1, z2));
      float e0 = expf(z0 - mx), e1 = expf(z1 - mx), e2 = expf(z2 - mx);
      float inv = 1.f / (e0 + e1 + e2);
      float* gp = gates + ((size_t)p * T_TOK + t) * 3;
      gp[0] = e0 * inv;
      gp[1] = e1 * inv;
      gp[2] = e2 * inv;
    }
  }
}

// ---------------------------------------------------------------------------
// Kernel P1: split x (fp32) -> xh + xl (f16 hi/lo), same [t][k] layout.
// ---------------------------------------------------------------------------
__global__ __launch_bounds__(256) void split_x_kernel(
    const float* __restrict__ x, _Float16* __restrict__ xh, _Float16* __restrict__ xl) {
  const size_t i = ((size_t)blockIdx.x * 256 + threadIdx.x) * 4;
  const float4 v = *(const float4*)(x + i);
  f16x4 h, lo;
  h[0] = (_Float16)v.x; lo[0] = (_Float16)(v.x - (float)h[0]);
  h[1] = (_Float16)v.y; lo[1] = (_Float16)(v.y - (float)h[1]);
  h[2] = (_Float16)v.z; lo[2] = (_Float16)(v.z - (float)h[2]);
  h[3] = (_Float16)v.w; lo[3] = (_Float16)(v.w - (float)h[3]);
  *(f16x4*)(xh + i) = h;
  *(f16x4*)(xl + i) = lo;
}

// ---------------------------------------------------------------------------
// Kernel P2: split + transpose W. Out: wh/wl[mat][c][k] f16 (k contiguous).
// ---------------------------------------------------------------------------
__global__ __launch_bounds__(256) void split_w_kernel(
    const float* __restrict__ Wq, const float* __restrict__ Wk, const float* __restrict__ Wv,
    _Float16* __restrict__ wh, _Float16* __restrict__ wl) {
  const int mat = blockIdx.y;
  const float* W = ((mat < 3) ? Wq : (mat < 6) ? Wk : Wv) + (size_t)(mat % 3) * 1048576;
  const int kt = (blockIdx.x >> 4) * 64, ct = (blockIdx.x & 15) * 64;
  __shared__ _Float16 hs[64][72];
  __shared__ _Float16 ls[64][72];
  const int tid = threadIdx.x;
#pragma unroll
  for (int i = 0; i < 4; ++i) {
    const int r = (tid >> 4) + i * 16;
    const int c4 = (tid & 15) * 4;
    const float4 v = *(const float4*)(W + (size_t)(kt + r) * 1024 + ct + c4);
    _Float16 h;
    h = (_Float16)v.x; hs[c4 + 0][r] = h; ls[c4 + 0][r] = (_Float16)(v.x - (float)h);
    h = (_Float16)v.y; hs[c4 + 1][r] = h; ls[c4 + 1][r] = (_Float16)(v.y - (float)h);
    h = (_Float16)v.z; hs[c4 + 2][r] = h; ls[c4 + 2][r] = (_Float16)(v.z - (float)h);
    h = (_Float16)v.w; hs[c4 + 3][r] = h; ls[c4 + 3][r] = (_Float16)(v.w - (float)h);
  }
  __syncthreads();
#pragma unroll
  for (int i = 0; i < 2; ++i) {
    const int u = tid + i * 256;
    const int c = u >> 3, seg = u & 7;
    const size_t o = (size_t)mat * 1048576 + (size_t)(ct + c) * 1024 + kt + seg * 8;
    *(f16x8*)(wh + o) = *(const f16x8*)(&hs[c][seg * 8]);
    *(f16x8*)(wl + o) = *(const f16x8*)(&ls[c][seg * 8]);
  }
}

// ---------------------------------------------------------------------------
// Kernel 2 (MFMA): MoE expert GEMM, f16 hi/lo 3-pass, 32x32x16 MFMA.
// R6: ping-pong double-buffered LDS. 96 fused (expert,k)-steps, ONE barrier
// per step; prefetch for step s+1 issued right after the barrier so the
// vmcnt drain at the next barrier waits on loads that aged a full step.
// Gate folded in-register at expert boundaries.
// ---------------------------------------------------------------------------
__global__ __launch_bounds__(256, 2) void moe_mfma_kernel(
    const _Float16* __restrict__ xh, const _Float16* __restrict__ xl,
    const _Float16* __restrict__ wh, const _Float16* __restrict__ wl,
    const float* __restrict__ bq_, const float* __restrict__ bk_, const float* __restrict__ bv_,
    const float* __restrict__ gates,
    float* __restrict__ oq_, float* __restrict__ ok_, float* __restrict__ ov_) {
  const int p = blockIdx.z;
  const float* bias = (p == 0) ? bq_ : (p == 1) ? bk_ : bv_;
  float* out = (p == 0) ? oq_ : (p == 1) ? ok_ : ov_;

  __shared__ _Float16 Ah[2][128][32], Al[2][128][32];
  __shared__ _Float16 Bh[2][128][32], Bl[2][128][32];
  __shared__ float gsh[128][3];
  __shared__ float bsh[3][128];

  const int tid = threadIdx.x;
  const int l = tid & 63, w = tid >> 6;
  const int wm = w & 1, wn = w >> 1;
  const int row0 = blockIdx.x * 128, col0 = blockIdx.y * 128;

  for (int i = tid; i < 384; i += 256)
    gsh[i / 3][i % 3] = gates[((size_t)p * T_TOK + row0 + i / 3) * 3 + (i % 3)];
  for (int i = tid; i < 384; i += 256)
    bsh[i >> 7][i & 127] = bias[(i >> 7) * 1024 + col0 + (i & 127)];

  const int m = l & 31, half = l >> 5;
  const int S = (m >> 1) & 3;
  const int rr = l >> 2;
  const int gc = (l & 3) ^ ((l >> 3) & 3);
  const size_t aoff = (size_t)(row0 + w * 32 + rr) * 1024 + gc * 8;
  const size_t wcol = ((size_t)col0 + w * 32 + rr) * 1024 + gc * 8;

  // stage step seq into buffer buf (8 async16 per lane-group; wave covers
  // its 32 rows of all four tiles).
  auto stage = [&](int seq, int buf) {
    const int e = seq >> 5;
    const int k0 = (seq & 31) << 5;
    const size_t wb = (size_t)(p * 3 + e) * 1048576 + wcol;
    async16(xh + aoff + k0,             &Ah[buf][w * 32][0]);
    async16(xh + aoff + k0 + 16 * 1024, &Ah[buf][w * 32 + 16][0]);
    async16(xl + aoff + k0,             &Al[buf][w * 32][0]);
    async16(xl + aoff + k0 + 16 * 1024, &Al[buf][w * 32 + 16][0]);
    async16(wh + wb + k0,               &Bh[buf][w * 32][0]);
    async16(wh + wb + k0 + 16 * 1024,   &Bh[buf][w * 32 + 16][0]);
    async16(wl + wb + k0,               &Bl[buf][w * 32][0]);
    async16(wl + wb + k0 + 16 * 1024,   &Bl[buf][w * 32 + 16][0]);
  };

  f32x16 fin[2][2], acc[2][2];
#pragma unroll
  for (int i = 0; i < 2; ++i)
#pragma unroll
    for (int j = 0; j < 2; ++j)
#pragma unroll
      for (int r = 0; r < 16; ++r) { fin[i][j][r] = 0.f; acc[i][j][r] = 0.f; }

  stage(0, 0);

#pragma unroll 2
  for (int seq = 0; seq < 96; ++seq) {
    const int buf = seq & 1;
    __syncthreads();  // buf ready (drains prefetch aged one full step); WAR on buf^1
    if (seq < 95) stage(seq + 1, buf ^ 1);

#pragma unroll
    for (int ss = 0; ss < 2; ++ss) {
      const int ch = ((ss << 1) | half) ^ S;
      f16x8 a_h[2], a_l[2], b_h[2], b_l[2];
#pragma unroll
      for (int i = 0; i < 2; ++i) {
        const int rA = wm * 64 + i * 32 + m;
        a_h[i] = *(const f16x8*)(&Ah[buf][rA][ch * 8]);
        a_l[i] = *(const f16x8*)(&Al[buf][rA][ch * 8]);
        const int rB = wn * 64 + i * 32 + m;
        b_h[i] = *(const f16x8*)(&Bh[buf][rB][ch * 8]);
        b_l[i] = *(const f16x8*)(&Bl[buf][rB][ch * 8]);
      }
#pragma unroll
      for (int i = 0; i < 2; ++i)
#pragma unroll
        for (int j = 0; j < 2; ++j) {
          acc[i][j] = __builtin_amdgcn_mfma_f32_32x32x16_f16(a_h[i], b_h[j], acc[i][j], 0, 0, 0);
          acc[i][j] = __builtin_amdgcn_mfma_f32_32x32x16_f16(a_h[i], b_l[j], acc[i][j], 0, 0, 0);
          acc[i][j] = __builtin_amdgcn_mfma_f32_32x32x16_f16(a_l[i], b_h[j], acc[i][j], 0, 0, 0);
        }
    }

    if ((seq & 31) == 31) {  // expert boundary: fold gate, reset acc
      const int e = seq >> 5;
#pragma unroll
      for (int i = 0; i < 2; ++i)
#pragma unroll
        for (int r = 0; r < 16; ++r) {
          const int row_l = wm * 64 + i * 32 + (r & 3) + ((r >> 2) << 3) + (half << 2);
          const float g = gsh[row_l][e];
#pragma unroll
          for (int j = 0; j < 2; ++j) {
            fin[i][j][r] += g * acc[i][j][r];
            acc[i][j][r] = 0.f;
          }
        }
    }
  }

#pragma unroll
  for (int j = 0; j < 2; ++j) {
    const int col_l = wn * 64 + j * 32 + m;
    const float b0 = bsh[0][col_l], b1 = bsh[1][col_l], b2 = bsh[2][col_l];
#pragma unroll
    for (int i = 0; i < 2; ++i)
#pragma unroll
      for (int r = 0; r < 16; ++r) {
        const int row_l = wm * 64 + i * 32 + (r & 3) + ((r >> 2) << 3) + (half << 2);
        const float g0 = gsh[row_l][0], g1 = gsh[row_l][1], g2 = gsh[row_l][2];
        out[(size_t)(row0 + row_l) * 1024 + col0 + col_l] =
            fin[i][j][r] + g0 * b0 + g1 * b1 + g2 * b2;
      }
  }
}

// ---------------------------------------------------------------------------
// Kernel P3: repack f32 [t][e] -> chunk-swizzled f16 hi/lo [t][e'].
// ---------------------------------------------------------------------------
__global__ __launch_bounds__(256) void repack_qk_kernel(
    const float* __restrict__ src, _Float16* __restrict__ h, _Float16* __restrict__ lo,
    float scale) {
  const size_t i = ((size_t)blockIdx.x * 256 + threadIdx.x) * 4;
  float4 v = *(const float4*)(src + i);
  v.x *= scale; v.y *= scale; v.z *= scale; v.w *= scale;
  const int t = (int)(i >> 10);
  const int e = (int)(i & 1023);
  const int d = e & 63, c = d >> 3, j = d & 7;  // j in {0,4}
  const size_t dst = (i & ~(size_t)63) + (size_t)(((c ^ (t & 7)) << 3) | j);
  f16x4 hh, ll;
  hh[0] = (_Float16)v.x; ll[0] = (_Float16)(v.x - (float)hh[0]);
  hh[1] = (_Float16)v.y; ll[1] = (_Float16)(v.y - (float)hh[1]);
  hh[2] = (_Float16)v.z; ll[2] = (_Float16)(v.z - (float)hh[2]);
  hh[3] = (_Float16)v.w; ll[3] = (_Float16)(v.w - (float)hh[3]);
  *(f16x4*)(h + dst) = hh;
  *(f16x4*)(lo + dst) = ll;
}

// ---------------------------------------------------------------------------
// Kernel P4: transpose V -> vT[(mi*16+h)*64 + d][2048 s] f16 hi/lo,
// chunk-swizzled within each 64-aligned s-tile: chunk kc at kc ^ (d&7).
// ---------------------------------------------------------------------------
__global__ __launch_bounds__(256) void repack_vT_kernel(
    const float* __restrict__ xv, _Float16* __restrict__ vth, _Float16* __restrict__ vtl) {
  const int mh = blockIdx.y;
  const int s0 = blockIdx.x * 64;
  __shared__ _Float16 hs[64][72];  // [d][s]
  __shared__ _Float16 ls[64][72];
  const int tid = threadIdx.x;
#pragma unroll
  for (int i = 0; i < 4; ++i) {
    const int idx = tid + i * 256;
    const int sr = idx >> 4;
    const int c4 = (idx & 15) * 4;
    const float4 v = *(const float4*)(
        xv + ((size_t)(mh >> 4) * S_LEN + s0 + sr) * 1024 + (mh & 15) * 64 + c4);
    _Float16 h;
    h = (_Float16)v.x; hs[c4 + 0][sr] = h; ls[c4 + 0][sr] = (_Float16)(v.x - (float)h);
    h = (_Float16)v.y; hs[c4 + 1][sr] = h; ls[c4 + 1][sr] = (_Float16)(v.y - (float)h);
    h = (_Float16)v.z; hs[c4 + 2][sr] = h; ls[c4 + 2][sr] = (_Float16)(v.z - (float)h);
    h = (_Float16)v.w; hs[c4 + 3][sr] = h; ls[c4 + 3][sr] = (_Float16)(v.w - (float)h);
  }
  __syncthreads();
#pragma unroll
  for (int i = 0; i < 2; ++i) {
    const int u = tid + i * 256;
    const int d = u >> 3, kc = u & 7;
    const int phys = kc ^ (d & 7);
    const size_t o = ((size_t)mh * 64 + d) * (size_t)S_LEN + s0 + phys * 8;
    *(f16x8*)(vth + o) = *(const f16x8*)(&hs[d][kc * 8]);
    *(f16x8*)(vtl + o) = *(const f16x8*)(&ls[d][kc * 8]);
  }
}

// ---------------------------------------------------------------------------
// Kernel 3 (MFMA): flash attention, f16 hi/lo 3-pass. (unchanged from R5)
// ---------------------------------------------------------------------------
__global__ __launch_bounds__(256, 3) void attn_mfma_kernel(
    const _Float16* __restrict__ qh, const _Float16* __restrict__ ql,
    const _Float16* __restrict__ kh, const _Float16* __restrict__ kl,
    const _Float16* __restrict__ vth, const _Float16* __restrict__ vtl,
    float* __restrict__ out) {
  __shared__ __align__(16) char KSraw[16640];   // Kh | Kl ; overlaid: S f32 stride 65
  __shared__ __align__(16) char QPraw[16384];   // Qh | Ql ; overlaid: Ph | Pl
  __shared__ __align__(16) char VTraw[16384];   // VTh | VTl
  __shared__ float alphas[64];
  __shared__ float lstate[64];

  _Float16* Kh = (_Float16*)KSraw;
  _Float16* Kl = Kh + 4096;
  float* Sb = (float*)KSraw;          // [64][65]
  _Float16* Qh = (_Float16*)QPraw;    // == Ph
  _Float16* Ql = Qh + 4096;           // == Pl
  _Float16* VTh = (_Float16*)VTraw;
  _Float16* VTl = VTh + 4096;

  const int tid = threadIdx.x;
  const int l = tid & 63, w = tid >> 6;
  const int wm = w & 1, wn = w >> 1;
  const int m = l & 31, half = l >> 5;
  const int key = m & 7;
  const int qt0 = blockIdx.x * 64;
  const int mh = blockIdx.y;          // mi*16 + h
  const int mi = mh >> 4, h = mh & 15;
  const size_t tok0 = (size_t)mi * S_LEN;   // batch token offset

  // staging lane constants
  const int r8 = l >> 3, c8 = l & 7;

  // ---- stage Q (once) ----
  {
    const size_t g0 = (tok0 + qt0 + w * 16 + r8) * 1024 + h * 64 + c8 * 8;
    async16(qh + g0,            Qh + (w * 16) * 64);
    async16(qh + g0 + 8 * 1024, Qh + (w * 16 + 8) * 64);
    async16(ql + g0,            Ql + (w * 16) * 64);
    async16(ql + g0 + 8 * 1024, Ql + (w * 16 + 8) * 64);
  }
  __syncthreads();

  // ---- preload Q fragments into registers ----
  f16x8 qa_h[4], qa_l[4];
#pragma unroll
  for (int ks = 0; ks < 4; ++ks) {
    const int phys = (ks * 2 + half) ^ key;
    const int ro = (wm * 32 + m) * 64 + phys * 8;
    qa_h[ks] = *(const f16x8*)(Qh + ro);
    qa_l[ks] = *(const f16x8*)(Ql + ro);
  }

  const int sq = tid >> 2, part = tid & 3;  // softmax: 4 lanes per q-row
  const int k0 = part * 16;
  float mreg = -3.0e38f, lreg = 0.f;

  f32x16 o_acc;
#pragma unroll
  for (int r = 0; r < 16; ++r) o_acc[r] = 0.f;

  for (int jt = 0; jt < 32; ++jt) {
    const int kt0 = jt * 64;
    __syncthreads();  // prior iter's K/VT/P/S consumers done

    // ---- stage K and VT ----
    {
      const size_t g0 = (tok0 + kt0 + w * 16 + r8) * 1024 + h * 64 + c8 * 8;
      async16(kh + g0,            Kh + (w * 16) * 64);
      async16(kh + g0 + 8 * 1024, Kh + (w * 16 + 8) * 64);
      async16(kl + g0,            Kl + (w * 16) * 64);
      async16(kl + g0 + 8 * 1024, Kl + (w * 16 + 8) * 64);
      const size_t v0 = ((size_t)mh * 64 + w * 16 + r8) * (size_t)S_LEN + kt0 + c8 * 8;
      async16(vth + v0,            VTh + (w * 16) * 64);
      async16(vth + v0 + 8 * 2048, VTh + (w * 16 + 8) * 64);
      async16(vtl + v0,            VTl + (w * 16) * 64);
      async16(vtl + v0 + 8 * 2048, VTl + (w * 16 + 8) * 64);
    }
    __syncthreads();

    // ---- QK^T (3-pass hi/lo) ----
    f32x16 s_acc;
#pragma unroll
    for (int r = 0; r < 16; ++r) s_acc[r] = 0.f;
#pragma unroll
    for (int ks = 0; ks < 4; ++ks) {
      const int phys = (ks * 2 + half) ^ key;
      const int bo = (wn * 32 + m) * 64 + phys * 8;
      const f16x8 kb_h = *(const f16x8*)(Kh + bo);
      const f16x8 kb_l = *(const f16x8*)(Kl + bo);
      s_acc = __builtin_amdgcn_mfma_f32_32x32x16_f16(qa_h[ks], kb_h, s_acc, 0, 0, 0);
      s_acc = __builtin_amdgcn_mfma_f32_32x32x16_f16(qa_h[ks], kb_l, s_acc, 0, 0, 0);
      s_acc = __builtin_amdgcn_mfma_f32_32x32x16_f16(qa_l[ks], kb_h, s_acc, 0, 0, 0);
    }
    __syncthreads();  // all K frag reads done -> S may overwrite K region

    // ---- write S (f32, stride 65: conflict-free) ----
#pragma unroll
    for (int r = 0; r < 16; ++r) {
      const int row = wm * 32 + (r & 3) + ((r >> 2) << 3) + (half << 2);
      Sb[row * 65 + wn * 32 + m] = s_acc[r];
    }
    __syncthreads();

    // ---- online softmax (row sq, k-segment part*16..+15) ----
    {
      float pv[16];
      float mc = -3.0e38f;
#pragma unroll
      for (int k2 = 0; k2 < 16; ++k2) {
        pv[k2] = Sb[sq * 65 + k0 + k2];
        mc = fmaxf(mc, pv[k2]);
      }
      mc = fmaxf(mc, __shfl_xor(mc, 1, 64));
      mc = fmaxf(mc, __shfl_xor(mc, 2, 64));
      const float mn = fmaxf(mreg, mc);
      float rs = 0.f;
#pragma unroll
      for (int k2 = 0; k2 < 16; ++k2) {
        const float pe = __expf(pv[k2] - mn);
        pv[k2] = pe;
        rs += pe;
      }
      rs += __shfl_xor(rs, 1, 64);
      rs += __shfl_xor(rs, 2, 64);
      const float al = __expf(mreg - mn);
      lreg = lreg * al + rs;
      mreg = mn;
      if (part == 0) alphas[sq] = al;
      // pack P -> f16 hi/lo, chunk-swizzled rows (key sq&7)
      const int skey = sq & 7;
      f16x8 p_h, p_l;
#pragma unroll
      for (int z = 0; z < 8; ++z) {
        p_h[z] = (_Float16)pv[z];
        p_l[z] = (_Float16)(pv[z] - (float)p_h[z]);
      }
      int phys = (2 * part) ^ skey;
      *(f16x8*)(Qh + sq * 64 + phys * 8) = p_h;   // Ph
      *(f16x8*)(Ql + sq * 64 + phys * 8) = p_l;   // Pl
#pragma unroll
      for (int z = 0; z < 8; ++z) {
        p_h[z] = (_Float16)pv[8 + z];
        p_l[z] = (_Float16)(pv[8 + z] - (float)p_h[z]);
      }
      phys = (2 * part + 1) ^ skey;
      *(f16x8*)(Qh + sq * 64 + phys * 8) = p_h;
      *(f16x8*)(Ql + sq * 64 + phys * 8) = p_l;
    }
    __syncthreads();

    // ---- O = O*alpha + P·V (3-pass hi/lo) ----
#pragma unroll
    for (int r = 0; r < 16; ++r) {
      const int row = wm * 32 + (r & 3) + ((r >> 2) << 3) + (half << 2);
      o_acc[r] *= alphas[row];
    }
#pragma unroll
    for (int ks = 0; ks < 4; ++ks) {
      const int phys = (ks * 2 + half) ^ key;
      const int po = (wm * 32 + m) * 64 + phys * 8;
      const f16x8 pa_h = *(const f16x8*)(Qh + po);
      const f16x8 pa_l = *(const f16x8*)(Ql + po);
      const int vo = (wn * 32 + m) * 64 + phys * 8;
      const f16x8 vb_h = *(const f16x8*)(VTh + vo);
      const f16x8 vb_l = *(const f16x8*)(VTl + vo);
      o_acc = __builtin_amdgcn_mfma_f32_32x32x16_f16(pa_h, vb_h, o_acc, 0, 0, 0);
      o_acc = __builtin_amdgcn_mfma_f32_32x32x16_f16(pa_h, vb_l, o_acc, 0, 0, 0);
      o_acc = __builtin_amdgcn_mfma_f32_32x32x16_f16(pa_l, vb_h, o_acc, 0, 0, 0);
    }
  }

  // ---- epilogue ----
  if (part == 0) lstate[sq] = lreg;
  __syncthreads();
#pragma unroll
  for (int r = 0; r < 16; ++r) {
    const int row = wm * 32 + (r & 3) + ((r >> 2) << 3) + (half << 2);
    const float linv = 1.f / lstate[row];
    out[(tok0 + qt0 + row) * 1024 + h * 64 + wn * 32 + m] = o_acc[r] * linv;
  }
}

// ---------------------------------------------------------------------------
// Fallback kernels (fp32), used only if ws_size too small.
// ---------------------------------------------------------------------------
__global__ __launch_bounds__(256) void moe_gemm_kernel(
    const float* __restrict__ x,
    const float* __restrict__ Wq_, const float* __restrict__ bq_,
    const float* __restrict__ Wk_, const float* __restrict__ bk_,
    const float* __restrict__ Wv_, const float* __restrict__ bv_,
    const float* __restrict__ gates,
    float* __restrict__ oq_, float* __restrict__ ok_, float* __restrict__ ov_) {
  const int p = blockIdx.z;
  const float* W = (p == 0) ? Wq_ : (p == 1) ? Wk_ : Wv_;
  const float* bias = (p == 0) ? bq_ : (p == 1) ? bk_ : bv_;
  float* out = (p == 0) ? oq_ : (p == 1) ? ok_ : ov_;
  const float* gbase = gates + (size_t)p * T_TOK * 3;

  __shared__ float AsT[8][128];
  __shared__ float Bs[8][128];
  __shared__ float gsh[128][3];

  const int tid = threadIdx.x;
  const int tx = tid & 15;
  const int ty = tid >> 4;
  const int row0 = blockIdx.x * 128;
  const int col0 = blockIdx.y * 128;

  for (int i = tid; i < 384; i += 256)
    gsh[i / 3][i % 3] = gbase[(size_t)(row0 + i / 3) * 3 + (i % 3)];

  float acc[8][8];
#pragma unroll
  for (int i = 0; i < 8; ++i)
#pragma unroll
    for (int j = 0; j < 8; ++j) acc[i][j] = 0.f;

  __syncthreads();

  const int ar = tid >> 1;
  const int ac = (tid & 1) << 2;
  const int br = tid >> 5;
  const int bc = (tid & 31) << 2;
  const float* xrow = x + (size_t)(row0 + ar) * E_DIM + ac;

  for (int kk = 0; kk < 3072; kk += 8) {
    const int n = kk >> 10;
    const int k = kk & 1023;
    const float g = gsh[ar][n];
    const float4 av = *(const float4*)(xrow + k);
    AsT[ac + 0][ar] = av.x * g;
    AsT[ac + 1][ar] = av.y * g;
    AsT[ac + 2][ar] = av.z * g;
    AsT[ac + 3][ar] = av.w * g;
    *(float4*)(&Bs[br][bc]) =
        *(const float4*)(W + (size_t)n * 1048576 + (size_t)(k + br) * 1024 + col0 + bc);
    __syncthreads();
#pragma unroll
    for (int kq = 0; kq < 8; ++kq) {
      const float4 a0 = *(const float4*)(&AsT[kq][ty * 4]);
      const float4 a1 = *(const float4*)(&AsT[kq][64 + ty * 4]);
      const float4 b0 = *(const float4*)(&Bs[kq][tx * 4]);
      const float4 b1 = *(const float4*)(&Bs[kq][64 + tx * 4]);
      const float a[8] = {a0.x, a0.y, a0.z, a0.w, a1.x, a1.y, a1.z, a1.w};
      const float b[8] = {b0.x, b0.y, b0.z, b0.w, b1.x, b1.y, b1.z, b1.w};
#pragma unroll
      for (int i = 0; i < 8; ++i)
#pragma unroll
        for (int j = 0; j < 8; ++j) acc[i][j] = fmaf(a[i], b[j], acc[i][j]);
    }
    __syncthreads();
  }

#pragma unroll
  for (int ih = 0; ih < 2; ++ih) {
#pragma unroll
    for (int i = 0; i < 4; ++i) {
      const int rl = ih * 64 + ty * 4 + i;
      const float g0 = gsh[rl][0], g1 = gsh[rl][1], g2 = gsh[rl][2];
      float* orow = out + (size_t)(row0 + rl) * E_DIM;
#pragma unroll
      for (int jh = 0; jh < 2; ++jh) {
        const int cl = jh * 64 + tx * 4;
        const int c = col0 + cl;
        float4 v;
        v.x = acc[ih * 4 + i][jh * 4 + 0] + g0 * bias[c + 0] + g1 * bias[1024 + c + 0] + g2 * bias[2048 + c + 0];
        v.y = acc[ih * 4 + i][jh * 4 + 1] + g0 * bias[c + 1] + g1 * bias[1024 + c + 1] + g2 * bias[2048 + c + 1];
        v.z = acc[ih * 4 + i][jh * 4 + 2] + g0 * bias[c + 2] + g1 * bias[1024 + c + 2] + g2 * bias[2048 + c + 2];
        v.w = acc[ih * 4 + i][jh * 4 + 3] + g0 * bias[c + 3] + g1 * bias[1024 + c + 3] + g2 * bias[2048 + c + 3];
        *(float4*)(orow + c) = v;
      }
    }
  }
}

__global__ __launch_bounds__(256) void attn_kernel(
    const float* __restrict__ xq, const float* __restrict__ xk,
    const float* __restrict__ xv, float* __restrict__ out) {
  __shared__ float QsT[64][64];
  __shared__ float KsT[64][64];
  __shared__ float Vs[64][64];
  __shared__ float Ss[64][65];
  __shared__ float mstate[64], lstate[64], alphas[64];

  const int tid = threadIdx.x;
  const int tx = tid & 15;
  const int ty = tid >> 4;
  const int qt0 = blockIdx.x * 64;
  const int mh = blockIdx.y;
  const int mi = mh >> 4, h = mh & 15;
  const size_t base = ((size_t)mi * S_LEN) * E_DIM + (size_t)h * 64;

  for (int it = tid; it < 1024; it += 256) {
    const int row = it >> 4, c4 = (it & 15) << 2;
    const float4 qv = *(const float4*)(xq + base + (size_t)(qt0 + row) * E_DIM + c4);
    QsT[c4 + 0][row] = qv.x;
    QsT[c4 + 1][row] = qv.y;
    QsT[c4 + 2][row] = qv.z;
    QsT[c4 + 3][row] = qv.w;
  }
  if (tid < 64) {
    mstate[tid] = -3.0e38f;
    lstate[tid] = 0.f;
  }
  float o[4][4];
#pragma unroll
  for (int i = 0; i < 4; ++i)
#pragma unroll
    for (int j = 0; j < 4; ++j) o[i][j] = 0.f;

  for (int jt = 0; jt < 32; ++jt) {
    __syncthreads();
    const int kt0 = jt * 64;
    for (int it = tid; it < 1024; it += 256) {
      const int row = it >> 4, c4 = (it & 15) << 2;
      const size_t ga = base + (size_t)(kt0 + row) * E_DIM + c4;
      const float4 kv = *(const float4*)(xk + ga);
      KsT[c4 + 0][row] = kv.x;
      KsT[c4 + 1][row] = kv.y;
      KsT[c4 + 2][row] = kv.z;
      KsT[c4 + 3][row] = kv.w;
      *(float4*)(&Vs[row][c4]) = *(const float4*)(xv + ga);
    }
    __syncthreads();

    float s[4][4];
#pragma unroll
    for (int i = 0; i < 4; ++i)
#pragma unroll
      for (int j = 0; j < 4; ++j) s[i][j] = 0.f;
#pragma unroll 8
    for (int d = 0; d < 64; ++d) {
      const float4 a4 = *(const float4*)(&QsT[d][ty * 4]);
      const float4 b4 = *(const float4*)(&KsT[d][tx * 4]);
      const float a[4] = {a4.x, a4.y, a4.z, a4.w};
      const float b[4] = {b4.x, b4.y, b4.z, b4.w};
#pragma unroll
      for (int i = 0; i < 4; ++i)
#pragma unroll
        for (int j = 0; j < 4; ++j) s[i][j] = fmaf(a[i], b[j], s[i][j]);
    }
#pragma unroll
    for (int i = 0; i < 4; ++i)
#pragma unroll
      for (int j = 0; j < 4; ++j) Ss[ty * 4 + i][tx * 4 + j] = s[i][j] * 0.125f;
    __syncthreads();

    {
      const int q = tid >> 2, part = tid & 3;
      const int k0 = part * 16;
      const float mprev = mstate[q];
      float mcur = -3.0e38f;
#pragma unroll
      for (int k2 = 0; k2 < 16; ++k2) mcur = fmaxf(mcur, Ss[q][k0 + k2]);
      mcur = fmaxf(mcur, __shfl_xor(mcur, 1, 64));
      mcur = fmaxf(mcur, __shfl_xor(mcur, 2, 64));
      const float mnew = fmaxf(mprev, mcur);
      float rs = 0.f;
#pragma unroll
      for (int k2 = 0; k2 < 16; ++k2) {
        const float pv = __expf(Ss[q][k0 + k2] - mnew);
        Ss[q][k0 + k2] = pv;
        rs += pv;
      }
      rs += __shfl_xor(rs, 1, 64);
      rs += __shfl_xor(rs, 2, 64);
      if (part == 0) {
        const float alpha = __expf(mprev - mnew);
        lstate[q] = lstate[q] * alpha + rs;
        mstate[q] = mnew;
        alphas[q] = alpha;
      }
    }
    __syncthreads();

    float al[4];
#pragma unroll
    for (int i = 0; i < 4; ++i) al[i] = alphas[ty * 4 + i];
#pragma unroll
    for (int i = 0; i < 4; ++i)
#pragma unroll
      for (int j = 0; j < 4; ++j) o[i][j] *= al[i];
#pragma unroll 8
    for (int k2 = 0; k2 < 64; ++k2) {
      float pr[4];
#pragma unroll
      for (int i = 0; i < 4; ++i) pr[i] = Ss[ty * 4 + i][k2];
      const float4 v4 = *(const float4*)(&Vs[k2][tx * 4]);
#pragma unroll
      for (int i = 0; i < 4; ++i) {
        o[i][0] = fmaf(pr[i], v4.x, o[i][0]);
        o[i][1] = fmaf(pr[i], v4.y, o[i][1]);
        o[i][2] = fmaf(pr[i], v4.z, o[i][2]);
        o[i][3] = fmaf(pr[i], v4.w, o[i][3]);
      }
    }
  }

#pragma unroll
  for (int i = 0; i < 4; ++i) {
    const float linv = 1.f / lstate[ty * 4 + i];
    float4 v;
    v.x = o[i][0] * linv;
    v.y = o[i][1] * linv;
    v.z = o[i][2] * linv;
    v.w = o[i][3] * linv;
    *(float4*)(out + base + (size_t)(qt0 + ty * 4 + i) * E_DIM + tx * 4) = v;
  }
}

// ---------------------------------------------------------------------------
extern "C" void kernel_launch(void* const* d_in, const int* in_sizes, int n_in,
                              void* d_out, int out_size, void* d_ws, size_t ws_size,
                              hipStream_t stream) {
  (void)in_sizes; (void)n_in; (void)out_size;
  const float* x   = (const float*)d_in[0];
  const float* Wq  = (const float*)d_in[1];
  const float* bq  = (const float*)d_in[2];
  const float* Wgq = (const float*)d_in[3];
  const float* bgq = (const float*)d_in[4];
  const float* Wk  = (const float*)d_in[5];
  const float* bk  = (const float*)d_in[6];
  const float* Wgk = (const float*)d_in[7];
  const float* bgk = (const float*)d_in[8];
  const float* Wv  = (const float*)d_in[9];
  const float* bv  = (const float*)d_in[10];
  const float* Wgv = (const float*)d_in[11];
  const float* bgv = (const float*)d_in[12];
  float* out = (float*)d_out;

  // layout: gates | xs_h | xs_l | wt_h | wt_l | xq | xk | xv
  // lifetime overlays (stream-ordered): qh<-xs_h, ql<-xs_l, kh<-wt_h,
  // kl<-wt_l (dead after moe); vth/vtl <- xq region (dead after repack_q).
  const size_t off_xsh = 294912;
  const size_t off_xsl = off_xsh + 16777216;
  const size_t off_wth = off_xsl + 16777216;
  const size_t off_wtl = off_wth + 18874368;
  const size_t off_xq  = off_wtl + 18874368;
  const size_t need_mfma = off_xq + 3ull * 33554432;  // ~164 MiB
  const size_t need_f32  = 294912 + 3ull * 33554432;  // ~101 MiB (fallback)

  float* gates = (float*)d_ws;

  if (ws_size >= need_mfma) {
    _Float16* xsh = (_Float16*)((char*)d_ws + off_xsh);
    _Float16* xsl = (_Float16*)((char*)d_ws + off_xsl);
    _Float16* wth = (_Float16*)((char*)d_ws + off_wth);
    _Float16* wtl = (_Float16*)((char*)d_ws + off_wtl);
    float* xq = (float*)((char*)d_ws + off_xq);
    float* xk = xq + (size_t)T_TOK * E_DIM;
    float* xv = xk + (size_t)T_TOK * E_DIM;
    // overlays
    _Float16* qh  = xsh;
    _Float16* ql  = xsl;
    _Float16* khb = wth;
    _Float16* klb = wtl;
    _Float16* vth = (_Float16*)((char*)d_ws + off_xq);
    _Float16* vtl = vth + 8388608;

    split_x_kernel<<<dim3(8192), dim3(256), 0, stream>>>(x, xsh, xsl);
    split_w_kernel<<<dim3(256, 9), dim3(256), 0, stream>>>(Wq, Wk, Wv, wth, wtl);
    gates_kernel<<<dim3(T_TOK), dim3(64), 0, stream>>>(x, Wgq, bgq, Wgk, bgk, Wgv, bgv, gates);
    moe_mfma_kernel<<<dim3(T_TOK / 128, E_DIM / 128, 3), dim3(256), 0, stream>>>(
        xsh, xsl, wth, wtl, bq, bk, bv, gates, xq, xk, xv);
    repack_qk_kernel<<<dim3(8192), dim3(256), 0, stream>>>(xq, qh, ql, 0.125f);
    repack_qk_kernel<<<dim3(8192), dim3(256), 0, stream>>>(xk, khb, klb, 1.0f);
    repack_vT_kernel<<<dim3(32, 64), dim3(256), 0, stream>>>(xv, vth, vtl);
    attn_mfma_kernel<<<dim3(32, 64), dim3(256), 0, stream>>>(qh, ql, khb, klb, vth, vtl, out);
  } else if (ws_size >= need_f32) {
    float* xq = (float*)((char*)d_ws + 294912);
    float* xk = xq + (size_t)T_TOK * E_DIM;
    float* xv = xk + (size_t)T_TOK * E_DIM;
    gates_kernel<<<dim3(T_TOK), dim3(64), 0, stream>>>(x, Wgq, bgq, Wgk, bgk, Wgv, bgv, gates);
    moe_gemm_kernel<<<dim3(T_TOK / 128, E_DIM / 128, 3), dim3(256), 0, stream>>>(
        x, Wq, bq, Wk, bk, Wv, bv, gates, xq, xk, xv);
    attn_kernel<<<dim3(S_LEN / 64, 64), dim3(256), 0, stream>>>(xq, xk, xv, out);
  }
}